// Round 5
// baseline (388.579 us; speedup 1.0000x reference)
//
#include <hip/hip_runtime.h>
#include <hip/hip_bf16.h>
#include <math.h>

// Problem constants
constexpr int N = 10000;
constexpr int E = 160000;
constexpr int B = 16;
constexpr int POOL_CHUNKS = 80;   // 80 * 125 = 10000
constexpr int MS = 72;            // m_s row stride (bf16), wave-local
constexpr int HS = 96;            // hb row stride: 4 q-sections x 24 (17 used + pad)

typedef short bf16x8 __attribute__((ext_vector_type(8)));
typedef short bf16x4 __attribute__((ext_vector_type(4)));
typedef float f32x4 __attribute__((ext_vector_type(4)));

__device__ __forceinline__ float silu_f(float x) {
    return x / (1.0f + __expf(-x));
}
__device__ __forceinline__ float bf2f(short s) {
    union { unsigned u; float f; } c; c.u = (unsigned)(unsigned short)s << 16; return c.f;
}

// ---------------- weight reorder bodies (q-major i-mapping) ----------------
__device__ __forceinline__ void w2_body(
        int idx, const float* __restrict__ Wsrc,
        __hip_bfloat16* __restrict__ Whi, __hip_bfloat16* __restrict__ Wlo) {
    int l = idx >> 15;
    int rem = idx & 32767;
    int kk = rem >> 11;
    int nt = (rem >> 9) & 3;
    int c  = (rem >> 5) & 15;
    int q  = (rem >> 3) & 3;
    int j  = rem & 7;
    int i = q * 16 + kk;
    int k = nt * 16 + c;
    float wv = Wsrc[(size_t)l * 32768 + i * 512 + j * 64 + k];
    __hip_bfloat16 hi = __float2bfloat16(wv);
    Whi[idx] = hi;
    Wlo[idx] = __float2bfloat16(wv - __bfloat162float(hi));
}

__device__ __forceinline__ void w2h_body(
        int idx, const float* __restrict__ Wsrc, __hip_bfloat16* __restrict__ Whi) {
    int l = idx >> 15;
    int rem = idx & 32767;
    int kk = rem >> 11;
    int nt = (rem >> 9) & 3;
    int c  = (rem >> 5) & 15;
    int q  = (rem >> 3) & 3;
    int j  = rem & 7;
    int i = q * 16 + kk;
    int k = nt * 16 + c;
    Whi[idx] = __float2bfloat16(Wsrc[(size_t)l * 32768 + i * 512 + j * 64 + k]);
}

__device__ __forceinline__ void wu1_body(
        int idx, const float* __restrict__ Wu1,
        __hip_bfloat16* __restrict__ Whi, __hip_bfloat16* __restrict__ Wlo) {
    int l = idx / 67584;
    int rem = idx % 67584;
    int kk = rem / 2048;          // 0..32
    int r2 = rem % 2048;
    int nt = (r2 >> 9) & 3;
    int c  = (r2 >> 5) & 15;
    int q  = (r2 >> 3) & 3;
    int j  = r2 & 7;
    int i = q * 33 + kk;          // 0..131
    float wv = (i < 129) ? Wu1[(size_t)l * 129 * 512 + i * 512 + j * 64 + nt * 16 + c] : 0.f;
    __hip_bfloat16 hi = __float2bfloat16(wv);
    Whi[idx] = hi;
    Wlo[idx] = __float2bfloat16(wv - __bfloat162float(hi));
}

__device__ __forceinline__ void wm1z_body(
        int idx, const float* __restrict__ Wm1, __hip_bfloat16* __restrict__ Whi) {
    int l = idx / 71680;
    int rem = idx % 71680;
    int kkn = rem >> 9;          // 0..139
    int off = rem & 511;
    int kk = kkn >> 2;
    int nt = kkn & 3;
    int c16 = off >> 5;
    int q = (off >> 3) & 3;
    int j = off & 7;
    int k = nt * 16 + c16;
    int wi = -1;
    if (kk < 17) { int i = q * 17 + kk; if (i <= 64) wi = i; }
    else if (kk < 34) { int s = q * 17 + (kk - 17); if (s <= 64) wi = 65 + s; }
    else { if (q == 0) wi = 130; }
    float wv = (wi >= 0) ? Wm1[((size_t)l * 131 + wi) * 512 + j * 64 + k] : 0.f;
    Whi[idx] = __float2bfloat16(wv);
}

// ---------------- mega pre-kernel: all weight reorders + hist zero + embed ----------------
constexpr int PB_W2H  = 0;                 // 256 blocks: Wm2 -> W2hi
constexpr int PB_WM1Z = PB_W2H  + 256;     // 560
constexpr int PB_WU1  = PB_WM1Z + 560;     // 528
constexpr int PB_WU2  = PB_WU1  + 528;     // 256
constexpr int PB_WP1  = PB_WU2  + 256;     // 128
constexpr int PB_WP2  = PB_WP1  + 128;     // 128
constexpr int PB_ZERO = PB_WP2  + 128;     // 40
constexpr int PB_EMB  = PB_ZERO + 40;      // 625
constexpr int PB_TOTAL= PB_EMB  + 625;     // 2521

__global__ __launch_bounds__(256) void k_pre(
        const float* __restrict__ Wm2, __hip_bfloat16* __restrict__ W2hi,
        const float* __restrict__ Wm1, __hip_bfloat16* __restrict__ Wm1zhi,
        const float* __restrict__ Wu1w, __hip_bfloat16* __restrict__ Wu1hi, __hip_bfloat16* __restrict__ Wu1lo,
        const float* __restrict__ Wu2w, __hip_bfloat16* __restrict__ Wu2hi, __hip_bfloat16* __restrict__ Wu2lo,
        const float* __restrict__ Wp1w, __hip_bfloat16* __restrict__ Wp1hi, __hip_bfloat16* __restrict__ Wp1lo,
        const float* __restrict__ Wp2w, __hip_bfloat16* __restrict__ Wp2hi, __hip_bfloat16* __restrict__ Wp2lo,
        int* __restrict__ hist,
        const float* __restrict__ x, const float* __restrict__ anf,
        const float* __restrict__ na, const float* __restrict__ W_emb,
        const float* __restrict__ b_emb,
        float* __restrict__ h, __hip_bfloat16* __restrict__ hb, float* __restrict__ agg) {
    __shared__ float xs[16][18];
    __shared__ float na_s[16][8];
    int tid = threadIdx.x;
    int bx = blockIdx.x;
    if (bx < PB_WM1Z) {
        w2h_body((bx - PB_W2H) * 256 + tid, Wm2, W2hi);
    } else if (bx < PB_WU1) {
        wm1z_body((bx - PB_WM1Z) * 256 + tid, Wm1, Wm1zhi);
    } else if (bx < PB_WU2) {
        wu1_body((bx - PB_WU1) * 256 + tid, Wu1w, Wu1hi, Wu1lo);
    } else if (bx < PB_WP1) {
        w2_body((bx - PB_WU2) * 256 + tid, Wu2w, Wu2hi, Wu2lo);
    } else if (bx < PB_WP2) {
        w2_body((bx - PB_WP1) * 256 + tid, Wp1w, Wp1hi, Wp1lo);
    } else if (bx < PB_ZERO) {
        w2_body((bx - PB_WP2) * 256 + tid, Wp2w, Wp2hi, Wp2lo);
    } else if (bx < PB_EMB) {
        int i = (bx - PB_ZERO) * 256 + tid;
        if (i < N) hist[i] = 0;
    } else {
        // ---- embed: h fp32 + hb (q-sectioned) + agg zero ----
        int eb = bx - PB_EMB;
        int w = tid >> 6, l = tid & 63;
        int n0 = eb * 16;
        {
            int r = tid >> 4, c = tid & 15;
            xs[r][c] = x[(size_t)(n0 + r) * 16 + c];
        }
        if (tid < 16) xs[tid][16] = anf[n0 + tid];
        if (tid < 128) na_s[tid >> 3][tid & 7] = na[(size_t)n0 * 8 + tid];
        float4 z4 = {0.f, 0.f, 0.f, 0.f};
        ((float4*)(agg + (size_t)eb * 1024))[tid] = z4;
        for (int t = tid; t < 192; t += 256)
            ((float4*)(hb + (size_t)n0 * HS))[t] = z4;
        __syncthreads();
        float acc[4];
#pragma unroll
        for (int t = 0; t < 4; ++t) acc[t] = b_emb[l];
        for (int i = 0; i < 17; ++i) {
#pragma unroll
            for (int j = 0; j < 8; ++j) {
                float wv = W_emb[(i * 8 + j) * 64 + l];
#pragma unroll
                for (int t = 0; t < 4; ++t) {
                    int nn = w * 4 + t;
                    acc[t] = fmaf(xs[nn][i] * na_s[nn][j], wv, acc[t]);
                }
            }
        }
        int slot = (l / 17) * 24 + l % 17;
#pragma unroll
        for (int t = 0; t < 4; ++t) {
            int n = n0 + w * 4 + t;
            h[(size_t)n * 64 + l] = acc[t];
            hb[(size_t)n * HS + slot] = __float2bfloat16(acc[t]);
        }
        if (tid < 16) hb[(size_t)(n0 + tid) * HS + 85] = __float2bfloat16(xs[tid][16]);
    }
}

// ---------------- edge sort by dst: histogram / scan / scatter+materialize ----------------
__global__ __launch_bounds__(256) void k_hist(
        const int* __restrict__ eidx, int* __restrict__ hist) {
    int e = blockIdx.x * 256 + threadIdx.x;
    if (e < E) atomicAdd(&hist[eidx[E + e]], 1);
}

// single-block exclusive scan over N=10000 bins -> cursor
__global__ __launch_bounds__(1024) void k_scan(
        const int* __restrict__ hist, int* __restrict__ cursor) {
    __shared__ int wsum[16];
    int t = threadIdx.x;
    int base = t * 10;
    int loc[10];
    int s = 0;
#pragma unroll
    for (int i = 0; i < 10; ++i) {
        int v = (base + i < N) ? hist[base + i] : 0;
        loc[i] = s;
        s += v;
    }
    int lane = t & 63, w = t >> 6;
    int incl = s;
    for (int off = 1; off < 64; off <<= 1) {
        int u = __shfl_up(incl, off, 64);
        if (lane >= off) incl += u;
    }
    if (lane == 63) wsum[w] = incl;
    __syncthreads();
    if (t == 0) {
        int a = 0;
        for (int i2 = 0; i2 < 16; ++i2) { int v = wsum[i2]; wsum[i2] = a; a += v; }
    }
    __syncthreads();
    int excl = incl - s + wsum[w];
#pragma unroll
    for (int i = 0; i < 10; ++i) {
        int p = base + i;
        if (p < N) cursor[p] = excl + loc[i];
    }
}

// scatter into dst-sorted records (coalesced reads; 48B record = 1-2 line touches/edge)
__global__ __launch_bounds__(256) void k_scatter_sort(
        const int* __restrict__ eidx, const float* __restrict__ ea,
        const float* __restrict__ amf, int* __restrict__ cursor,
        int* __restrict__ dstS, float4* __restrict__ recs) {
    int e = blockIdx.x * 256 + threadIdx.x;
    if (e < E) {
        int d = eidx[E + e];
        int p = atomicAdd(&cursor[d], 1);
        dstS[p] = d;
        float4 a0 = ((const float4*)ea)[(size_t)e * 2];
        float4 a1 = ((const float4*)ea)[(size_t)e * 2 + 1];
        float4 r0 = {__int_as_float(eidx[e]), amf[e], a0.x, a0.y};
        float4 r1 = {a0.z, a0.w, a1.x, a1.y};
        float4 r2 = {a1.z, a1.w, 0.f, 0.f};
        recs[(size_t)p * 3 + 0] = r0;
        recs[(size_t)p * 3 + 1] = r1;
        recs[(size_t)p * 3 + 2] = r2;
    }
}

// ---------------- device helper: one z-GEMM stage (hi/lo), 4 waves split K, q-major x ----------------
__device__ __forceinline__ void zgemm_stage(
        const __hip_bfloat16* xsrc, int xstride, int kkmax, int Lq,
        int w, int c16, int q, int lofs, const float* naA,
        const __hip_bfloat16* __restrict__ Whi, const __hip_bfloat16* __restrict__ Wlo,
        float (*part_s)[16][64]) {
    f32x4 zero4 = {0.f, 0.f, 0.f, 0.f};
    f32x4 acc[4];
#pragma unroll
    for (int nt = 0; nt < 4; ++nt) acc[nt] = zero4;
    for (int kk = w; kk < kkmax; kk += 4) {
        bf16x8 bh[4], bl[4];
#pragma unroll
        for (int nt = 0; nt < 4; ++nt) {
            int off = (kk * 4 + nt) * 512 + lofs;
            bh[nt] = *(const bf16x8*)(Whi + off);
            bl[nt] = *(const bf16x8*)(Wlo + off);
        }
        float mv = __bfloat162float(xsrc[c16 * xstride + q * Lq + kk]);
        union { bf16x8 v; __hip_bfloat16 hx[8]; } au;
#pragma unroll
        for (int j = 0; j < 8; ++j) au.hx[j] = __float2bfloat16(mv * naA[j]);
#pragma unroll
        for (int nt = 0; nt < 4; ++nt) {
            acc[nt] = __builtin_amdgcn_mfma_f32_16x16x32_bf16(au.v, bh[nt], acc[nt], 0, 0, 0);
            acc[nt] = __builtin_amdgcn_mfma_f32_16x16x32_bf16(au.v, bl[nt], acc[nt], 0, 0, 0);
        }
    }
#pragma unroll
    for (int nt = 0; nt < 4; ++nt)
#pragma unroll
        for (int r = 0; r < 4; ++r) part_s[w][q * 4 + r][nt * 16 + c16] = acc[nt][r];
}

// ---------------- K3: edge kernel — wave-private LDS, depth-2 weight prefetch ----------------
// launch_bounds (256,4): 128-VGPR budget. NOT (256,8): unified VGPR/AGPR file on gfx950;
// an 8-wave/EU floor leaves ~32 arch VGPRs -> total spill (r3: 852MB FETCH, 1.6GB WRITE).
// Grid supplies only ~4.9 blocks/CU so occupancy is grid-limited (r4: 34%); the lever is
// per-wave latency hiding: explicit depth-2 register dbuf of the weight stream (+~48 VGPR
// of in-flight loads) + re-convergence barriers every 8 chunks for intra-block L1 dedup.
__global__ __launch_bounds__(256, 4) void k_edge(
        const float4* __restrict__ recs, const int* __restrict__ dstS,
        const __hip_bfloat16* __restrict__ hb,
        const __hip_bfloat16* __restrict__ W1hi, const float* __restrict__ bm1_l,
        const __hip_bfloat16* __restrict__ W2hi,
        const float* __restrict__ bm2_l, float* __restrict__ agg) {
    // per-wave private 4608B region: m_s [32][72] bf16; m2 chunk [16][66] f32 overlaid
    __shared__ __align__(16) char smem_u[4 * 4608];   // 18432 B
    __shared__ int dst_s[128];
    int tid = threadIdx.x;
    int l = tid & 63, w = tid >> 6;
    int e0 = blockIdx.x * 128;
    __hip_bfloat16* m_s = (__hip_bfloat16*)(smem_u + w * 4608);
    float* m2 = (float*)(smem_u + w * 4608);

    if (l < 32) dst_s[w * 32 + l] = dstS[e0 + w * 32 + l];   // wave-private write+read

    int c16 = l & 15, q = l >> 4;
    int e0w = w * 32;
    float eaA[2][8], amfA[2];
    int dL[2], sL[2];
#pragma unroll
    for (int mt = 0; mt < 2; ++mt) {
        int e = e0 + e0w + mt * 16 + c16;
        float4 r0 = recs[(size_t)e * 3];
        float4 r1 = recs[(size_t)e * 3 + 1];
        float4 r2 = recs[(size_t)e * 3 + 2];
        sL[mt] = __float_as_int(r0.x);
        amfA[mt] = r0.y;
        eaA[mt][0] = r0.z; eaA[mt][1] = r0.w;
        eaA[mt][2] = r1.x; eaA[mt][3] = r1.y; eaA[mt][4] = r1.z; eaA[mt][5] = r1.w;
        eaA[mt][6] = r2.x; eaA[mt][7] = r2.y;
        dL[mt] = dstS[e];
    }
    float bR1[4], bR2[4];
#pragma unroll
    for (int nt = 0; nt < 4; ++nt) {
        bR1[nt] = bm1_l[nt * 16 + c16];
        bR2[nt] = bm2_l[nt * 16 + c16];
    }
    int lofs = (c16 * 4 + q) * 8;
    f32x4 zero4 = {0.f, 0.f, 0.f, 0.f};

    bf16x4 xD[2][5], xS[2][5];
#pragma unroll
    for (int mt = 0; mt < 2; ++mt) {
        const __hip_bfloat16* bd = hb + (size_t)dL[mt] * HS + q * 24;
        const __hip_bfloat16* bs = hb + (size_t)sL[mt] * HS + q * 24;
#pragma unroll
        for (int t = 0; t < 5; ++t) {
            xD[mt][t] = *(const bf16x4*)(bd + t * 4);
            xS[mt][t] = *(const bf16x4*)(bs + t * 4);
        }
    }

    // phase 1: unified W1 stream, u in [0,35): u<17 -> xD[u]; u<34 -> xS[u-17]; u==34 -> amf.
    // depth-2 register ring bhr[(u)%3] — all indices compile-time after full unroll.
    f32x4 acc1[2][4];
#pragma unroll
    for (int mt = 0; mt < 2; ++mt)
#pragma unroll
        for (int nt = 0; nt < 4; ++nt) acc1[mt][nt] = zero4;
    {
        bf16x8 bhr[3][4];
#pragma unroll
        for (int u = 0; u < 2; ++u)
#pragma unroll
            for (int nt = 0; nt < 4; ++nt)
                bhr[u][nt] = *(const bf16x8*)(W1hi + (u * 4 + nt) * 512 + lofs);
#pragma unroll
        for (int u = 0; u < 35; ++u) {
            if (u + 2 < 35) {
#pragma unroll
                for (int nt = 0; nt < 4; ++nt)
                    bhr[(u + 2) % 3][nt] = *(const bf16x8*)(W1hi + ((u + 2) * 4 + nt) * 512 + lofs);
            }
#pragma unroll
            for (int mt = 0; mt < 2; ++mt) {
                float xv;
                if (u < 17)       xv = bf2f(xD[mt][u >> 2][u & 3]);
                else if (u < 34)  { int s = u - 17; xv = bf2f(xS[mt][s >> 2][s & 3]); }
                else              xv = (q == 0) ? amfA[mt] : 0.f;
                union { bf16x8 v; __hip_bfloat16 hx[8]; } au;
#pragma unroll
                for (int j = 0; j < 8; ++j) au.hx[j] = __float2bfloat16(xv * eaA[mt][j]);
#pragma unroll
                for (int nt = 0; nt < 4; ++nt)
                    acc1[mt][nt] = __builtin_amdgcn_mfma_f32_16x16x32_bf16(au.v, bhr[u % 3][nt], acc1[mt][nt], 0, 0, 0);
            }
            if ((u & 7) == 7 && u < 34) __syncthreads();   // re-converge waves -> L1 dedup
        }
    }
    // stage m (wave-local rows 0..31)
#pragma unroll
    for (int mt = 0; mt < 2; ++mt)
#pragma unroll
        for (int nt = 0; nt < 4; ++nt) {
            int kd = nt * 16 + c16;
            float bias = bR1[nt];
#pragma unroll
            for (int r = 0; r < 4; ++r) {
                int el = mt * 16 + q * 4 + r;
                m_s[el * MS + kd] = __float2bfloat16(silu_f(bias + acc1[mt][nt][r]));
            }
        }

    // phase 2 (hi-only): read transposed m fragments
    bf16x4 mR[2][4];
#pragma unroll
    for (int mt = 0; mt < 2; ++mt)
#pragma unroll
        for (int t = 0; t < 4; ++t)
            mR[mt][t] = *(const bf16x4*)&m_s[(mt * 16 + c16) * MS + q * 16 + t * 4];

    // compiler barrier: m2 (float) writes below alias m_s (bf16) bytes — forbid TBAA reordering
    asm volatile("" ::: "memory");

    f32x4 acc[2][4];
#pragma unroll
    for (int mt = 0; mt < 2; ++mt)
#pragma unroll
        for (int nt = 0; nt < 4; ++nt) acc[mt][nt] = zero4;
    {
        bf16x8 bhr[3][4];
#pragma unroll
        for (int u = 0; u < 2; ++u)
#pragma unroll
            for (int nt = 0; nt < 4; ++nt)
                bhr[u][nt] = *(const bf16x8*)(W2hi + (u * 4 + nt) * 512 + lofs);
#pragma unroll
        for (int kk = 0; kk < 16; ++kk) {
            if (kk + 2 < 16) {
#pragma unroll
                for (int nt = 0; nt < 4; ++nt)
                    bhr[(kk + 2) % 3][nt] = *(const bf16x8*)(W2hi + ((kk + 2) * 4 + nt) * 512 + lofs);
            }
#pragma unroll
            for (int mt = 0; mt < 2; ++mt) {
                float mv = bf2f(mR[mt][kk >> 2][kk & 3]);
                union { bf16x8 v; __hip_bfloat16 h[8]; } au;
#pragma unroll
                for (int j = 0; j < 8; ++j) au.h[j] = __float2bfloat16(mv * eaA[mt][j]);
#pragma unroll
                for (int nt = 0; nt < 4; ++nt)
                    acc[mt][nt] = __builtin_amdgcn_mfma_f32_16x16x32_bf16(au.v, bhr[kk % 3][nt], acc[mt][nt], 0, 0, 0);
            }
            if (kk == 7) __syncthreads();                  // re-converge waves -> L1 dedup
        }
    }

    // chunked epilogue: per mt-chunk write 16 rows of m2 (own region), run-length reduce, atomics.
    // runs spanning chunk boundaries just produce one extra atomic — still exact.
#pragma unroll
    for (int mt = 0; mt < 2; ++mt) {
#pragma unroll
        for (int nt = 0; nt < 4; ++nt) {
            int kd = nt * 16 + c16;
            float bias = bR2[nt];
#pragma unroll
            for (int r = 0; r < 4; ++r)
                m2[(q * 4 + r) * 66 + kd] = silu_f(bias + acc[mt][nt][r]);
        }
        int rb = w * 32 + mt * 16;
        float run = 0.f;
        int cur_d = dst_s[rb];
        for (int i = 0; i < 16; ++i) {
            int d = dst_s[rb + i];                 // wave-uniform
            if (d != cur_d) {
                atomicAdd(&agg[(size_t)cur_d * 64 + l], run);
                run = 0.f;
                cur_d = d;
            }
            run += m2[i * 66 + l];
        }
        atomicAdd(&agg[(size_t)cur_d * 64 + l], run);
        asm volatile("" ::: "memory");             // chunk reads complete before next chunk overwrite
    }
}

// ---------------- K4: node update + write h/hb + agg zero ----------------
__global__ __launch_bounds__(256) void k_upd_hb(
        const float* __restrict__ h_in, const float* __restrict__ anf,
        const float* __restrict__ na, const float* __restrict__ agg_in,
        const __hip_bfloat16* __restrict__ W1hi, const __hip_bfloat16* __restrict__ W1lo,
        const float* __restrict__ bu1_l,
        const __hip_bfloat16* __restrict__ W2hi_, const __hip_bfloat16* __restrict__ W2lo_,
        const float* __restrict__ bu2_l,
        float* __restrict__ h, __hip_bfloat16* __restrict__ hb, float* __restrict__ agg) {
    __shared__ __align__(16) __hip_bfloat16 xa_s[16 * 136];
    __shared__ __align__(16) __hip_bfloat16 u1_s[16 * 72];
    __shared__ float part_s[4][16][64];
    int tid = threadIdx.x;
    int w = tid >> 6, l = tid & 63;
    int n0 = blockIdx.x * 16;
    for (int idx = tid; idx < 16 * 132; idx += 256) {
        int r = idx / 132, c = idx % 132;
        int n = n0 + r;
        float v;
        if (c < 64) v = h_in[(size_t)n * 64 + c];
        else if (c == 64) v = anf[n];
        else if (c < 129) v = agg_in[(size_t)n * 64 + (c - 65)];
        else v = 0.f;
        xa_s[r * 136 + c] = __float2bfloat16(v);
    }
    int c16 = l & 15, q = l >> 4;
    float naA[8];
#pragma unroll
    for (int j = 0; j < 8; ++j) naA[j] = na[(size_t)(n0 + c16) * 8 + j];
    __syncthreads();
    float4 z4 = {0.f, 0.f, 0.f, 0.f};
    ((float4*)(agg + (size_t)blockIdx.x * 1024))[tid] = z4;
    for (int t = tid; t < 192; t += 256)
        ((float4*)(hb + (size_t)n0 * HS))[t] = z4;
    int lofs = (c16 * 4 + q) * 8;
    zgemm_stage(xa_s, 136, 33, 33, w, c16, q, lofs, naA, W1hi, W1lo, part_s);
    __syncthreads();
    for (int t = tid; t < 1024; t += 256) {
        int row = t >> 6, col = t & 63;
        float v = part_s[0][row][col] + part_s[1][row][col] + part_s[2][row][col] +
                  part_s[3][row][col] + bu1_l[col];
        u1_s[row * 72 + col] = __float2bfloat16(silu_f(v));
    }
    __syncthreads();
    zgemm_stage(u1_s, 72, 16, 16, w, c16, q, lofs, naA, W2hi_, W2lo_, part_s);
    __syncthreads();
    for (int t = tid; t < 1024; t += 256) {
        int row = t >> 6, col = t & 63;
        float v = part_s[0][row][col] + part_s[1][row][col] + part_s[2][row][col] +
                  part_s[3][row][col] + bu2_l[col];
        int n = n0 + row;
        float hn = h[(size_t)n * 64 + col] + v;
        h[(size_t)n * 64 + col] = hn;
        hb[(size_t)n * HS + (col / 17) * 24 + col % 17] = __float2bfloat16(hn);
    }
    if (tid < 16) hb[(size_t)(n0 + tid) * HS + 85] = __float2bfloat16(anf[n0 + tid]);
}

// ---------------- K6: fused node update (layer 1) + prepool -> p2 ----------------
__global__ __launch_bounds__(256) void k_upd_prepool(
        const float* __restrict__ h_in, const float* __restrict__ anf,
        const float* __restrict__ na, const float* __restrict__ agg_in,
        const __hip_bfloat16* __restrict__ W1hi, const __hip_bfloat16* __restrict__ W1lo,
        const float* __restrict__ bu1_l,
        const __hip_bfloat16* __restrict__ W2hi_, const __hip_bfloat16* __restrict__ W2lo_,
        const float* __restrict__ bu2_l,
        const __hip_bfloat16* __restrict__ Wp1hi, const __hip_bfloat16* __restrict__ Wp1lo,
        const float* __restrict__ bp1,
        const __hip_bfloat16* __restrict__ Wp2hi, const __hip_bfloat16* __restrict__ Wp2lo,
        const float* __restrict__ bp2,
        float* __restrict__ p2) {
    __shared__ __align__(16) __hip_bfloat16 xa_s[16 * 136];
    __shared__ __align__(16) __hip_bfloat16 u1_s[16 * 72];
    __shared__ __align__(16) __hip_bfloat16 x2_s[16 * 72];
    __shared__ float part_s[4][16][64];
    int tid = threadIdx.x;
    int w = tid >> 6, l = tid & 63;
    int n0 = blockIdx.x * 16;
    for (int idx = tid; idx < 16 * 132; idx += 256) {
        int r = idx / 132, c = idx % 132;
        int n = n0 + r;
        float v;
        if (c < 64) v = h_in[(size_t)n * 64 + c];
        else if (c == 64) v = anf[n];
        else if (c < 129) v = agg_in[(size_t)n * 64 + (c - 65)];
        else v = 0.f;
        xa_s[r * 136 + c] = __float2bfloat16(v);
    }
    int c16 = l & 15, q = l >> 4;
    float naA[8];
#pragma unroll
    for (int j = 0; j < 8; ++j) naA[j] = na[(size_t)(n0 + c16) * 8 + j];
    __syncthreads();
    int lofs = (c16 * 4 + q) * 8;
    zgemm_stage(xa_s, 136, 33, 33, w, c16, q, lofs, naA, W1hi, W1lo, part_s);
    __syncthreads();
    for (int t = tid; t < 1024; t += 256) {
        int row = t >> 6, col = t & 63;
        float v = part_s[0][row][col] + part_s[1][row][col] + part_s[2][row][col] +
                  part_s[3][row][col] + bu1_l[col];
        u1_s[row * 72 + col] = __float2bfloat16(silu_f(v));
    }
    __syncthreads();
    zgemm_stage(u1_s, 72, 16, 16, w, c16, q, lofs, naA, W2hi_, W2lo_, part_s);
    __syncthreads();
    for (int t = tid; t < 1024; t += 256) {
        int row = t >> 6, col = t & 63;
        float v = part_s[0][row][col] + part_s[1][row][col] + part_s[2][row][col] +
                  part_s[3][row][col] + bu2_l[col];
        float hn = h_in[(size_t)(n0 + row) * 64 + col] + v;
        x2_s[row * 72 + col] = __float2bfloat16(hn);
    }
    __syncthreads();
    zgemm_stage(x2_s, 72, 16, 16, w, c16, q, lofs, naA, Wp1hi, Wp1lo, part_s);
    __syncthreads();
    for (int t = tid; t < 1024; t += 256) {
        int row = t >> 6, col = t & 63;
        float v = part_s[0][row][col] + part_s[1][row][col] + part_s[2][row][col] +
                  part_s[3][row][col] + bp1[col];
        u1_s[row * 72 + col] = __float2bfloat16(silu_f(v));
    }
    __syncthreads();
    zgemm_stage(u1_s, 72, 16, 16, w, c16, q, lofs, naA, Wp2hi, Wp2lo, part_s);
    __syncthreads();
    for (int t = tid; t < 1024; t += 256) {
        int row = t >> 6, col = t & 63;
        float v = part_s[0][row][col] + part_s[1][row][col] + part_s[2][row][col] +
                  part_s[3][row][col] + bp2[col];
        p2[(size_t)(n0 + row) * 64 + col] = v;
    }
}

// ---------------- K_pool ----------------
__global__ __launch_bounds__(256) void k_pool(
        const float* __restrict__ p2, const int* __restrict__ batch,
        float* __restrict__ partial_p, float* __restrict__ partial_cnt) {
    __shared__ float acc_s[16 * 64];
    __shared__ float cnt_s[16];
    int tid = threadIdx.x;
    for (int idx = tid; idx < 1024; idx += 256) acc_s[idx] = 0.f;
    if (tid < 16) cnt_s[tid] = 0.f;
    __syncthreads();
    int w = tid >> 6, k = tid & 63;
    int base = blockIdx.x * 125;
    for (int i = 0; i < 32; ++i) {
        int nl = i * 4 + w;
        if (nl < 125) {
            int n = base + nl;
            int b = batch[n];
            atomicAdd(&acc_s[b * 64 + k], p2[(size_t)n * 64 + k]);
            if (k == 0) atomicAdd(&cnt_s[b], 1.0f);
        }
    }
    __syncthreads();
    for (int idx = tid; idx < 1024; idx += 256)
        partial_p[(size_t)blockIdx.x * 1024 + idx] = acc_s[idx];
    if (tid < 16) partial_cnt[blockIdx.x * 16 + tid] = cnt_s[tid];
}

// ---------------- K7: reduce partials, mean, final MLP ----------------
__global__ __launch_bounds__(1024) void k_final(
        const float* __restrict__ partial_p, const float* __restrict__ partial_cnt,
        const float* __restrict__ Wq1, const float* __restrict__ bq1,
        const float* __restrict__ Wq2, const float* __restrict__ bq2,
        float* __restrict__ out) {
    __shared__ float g[16][64];
    int b = threadIdx.x >> 6, k = threadIdx.x & 63;
    float s = 0.f, cc = 0.f;
    for (int c = 0; c < POOL_CHUNKS; ++c) s += partial_p[(size_t)c * 1024 + b * 64 + k];
    for (int c = 0; c < POOL_CHUNKS; ++c) cc += partial_cnt[c * 16 + b];
    g[b][k] = s / fmaxf(cc, 1.0f);
    __syncthreads();
    float acc = bq1[k];
#pragma unroll
    for (int i = 0; i < 64; ++i) acc = fmaf(g[b][i], Wq1[i * 64 + k], acc);
    float v = silu_f(acc) * Wq2[k];
#pragma unroll
    for (int off = 32; off > 0; off >>= 1) v += __shfl_down(v, off, 64);
    if (k == 0) out[b] = v + bq2[0];
}

extern "C" void kernel_launch(void* const* d_in, const int* in_sizes, int n_in,
                              void* d_out, int out_size, void* d_ws, size_t ws_size,
                              hipStream_t stream) {
    const float* x    = (const float*)d_in[0];
    const int*   eidx = (const int*)  d_in[1];
    const float* ea   = (const float*)d_in[2];
    const float* na   = (const float*)d_in[3];
    const float* amf  = (const float*)d_in[4];
    const float* anf  = (const float*)d_in[5];
    const int*   batch= (const int*)  d_in[6];
    const float* W_emb= (const float*)d_in[7];
    const float* b_emb= (const float*)d_in[8];
    const float* Wm1  = (const float*)d_in[9];
    const float* bm1  = (const float*)d_in[10];
    const float* Wm2  = (const float*)d_in[11];
    const float* bm2  = (const float*)d_in[12];
    const float* Wu1  = (const float*)d_in[13];
    const float* bu1  = (const float*)d_in[14];
    const float* Wu2  = (const float*)d_in[15];
    const float* bu2  = (const float*)d_in[16];
    const float* Wp1  = (const float*)d_in[17];
    const float* bp1  = (const float*)d_in[18];
    const float* Wp2  = (const float*)d_in[19];
    const float* bp2  = (const float*)d_in[20];
    const float* Wq1  = (const float*)d_in[21];
    const float* bq1  = (const float*)d_in[22];
    const float* Wq2  = (const float*)d_in[23];
    const float* bq2  = (const float*)d_in[24];

    float* ws = (float*)d_ws;
    float* h      = ws;                            // N*64
    float* agg    = h + (size_t)N * 64;            // N*64
    float* p2     = agg + (size_t)N * 64;          // N*64
    float* part_p = p2 + (size_t)N * 64;           // 80*1024
    float* part_c = part_p + POOL_CHUNKS * 1024;   // 80*16
    float* fend   = part_c + POOL_CHUNKS * 16;
    __hip_bfloat16* hb     = (__hip_bfloat16*)fend;          // N*96
    __hip_bfloat16* W2hi   = hb + (size_t)N * HS;            // 2*32768
    __hip_bfloat16* Wm1zhi = W2hi + 65536;                   // 2*71680
    __hip_bfloat16* Wu1hi  = Wm1zhi + 143360;                // 2*67584
    __hip_bfloat16* Wu1lo  = Wu1hi + 135168;
    __hip_bfloat16* Wu2hi  = Wu1lo + 135168;                 // 2*32768
    __hip_bfloat16* Wu2lo  = Wu2hi + 65536;
    __hip_bfloat16* Wp1hi  = Wu2lo + 65536;                  // 32768
    __hip_bfloat16* Wp1lo  = Wp1hi + 32768;
    __hip_bfloat16* Wp2hi  = Wp1lo + 32768;
    __hip_bfloat16* Wp2lo  = Wp2hi + 32768;
    int* hist   = (int*)(Wp2lo + 32768);                     // N
    int* cursor = hist + N;                                  // N
    int* dstS   = cursor + N;                                // E
    float4* recs = (float4*)(dstS + E);                      // E * 3 float4 (48B/edge)

    // mega pre-kernel: all weight reorders + hist zero + embed(+agg/hb init)
    k_pre<<<PB_TOTAL, 256, 0, stream>>>(
        Wm2, W2hi, Wm1, Wm1zhi, Wu1, Wu1hi, Wu1lo, Wu2, Wu2hi, Wu2lo,
        Wp1, Wp1hi, Wp1lo, Wp2, Wp2hi, Wp2lo, hist,
        x, anf, na, W_emb, b_emb, h, hb, agg);

    // dst-sort + materialize sorted edge records (reused by both edge dispatches)
    k_hist<<<(E + 255) / 256, 256, 0, stream>>>(eidx, hist);
    k_scan<<<1, 1024, 0, stream>>>(hist, cursor);
    k_scatter_sort<<<(E + 255) / 256, 256, 0, stream>>>(eidx, ea, amf, cursor, dstS, recs);

    k_edge<<<E / 128, 256, 0, stream>>>(recs, dstS, hb,
                                        Wm1zhi, bm1, W2hi, bm2, agg);
    k_upd_hb<<<625, 256, 0, stream>>>(h, anf, na, agg,
                                      Wu1hi, Wu1lo, bu1,
                                      Wu2hi, Wu2lo, bu2,
                                      h, hb, agg);
    k_edge<<<E / 128, 256, 0, stream>>>(recs, dstS, hb,
                                        Wm1zhi + 71680, bm1 + 64,
                                        W2hi + 32768, bm2 + 64, agg);
    k_upd_prepool<<<625, 256, 0, stream>>>(h, anf, na, agg,
                                           Wu1hi + 67584, Wu1lo + 67584, bu1 + 64,
                                           Wu2hi + 32768, Wu2lo + 32768, bu2 + 64,
                                           Wp1hi, Wp1lo, bp1, Wp2hi, Wp2lo, bp2, p2);
    k_pool<<<POOL_CHUNKS, 256, 0, stream>>>(p2, batch, part_p, part_c);
    k_final<<<1, 1024, 0, stream>>>(part_p, part_c, Wq1, bq1, Wq2, bq2, (float*)d_out);
}

// Round 6
// 380.157 us; speedup vs baseline: 1.0222x; 1.0222x over previous
//
#include <hip/hip_runtime.h>
#include <hip/hip_bf16.h>
#include <math.h>

// Problem constants
constexpr int N = 10000;
constexpr int E = 160000;
constexpr int B = 16;
constexpr int POOL_CHUNKS = 80;   // 80 * 125 = 10000
constexpr int MS = 72;            // m_s row stride (bf16), wave-local
constexpr int HS = 96;            // hb row stride: 4 q-sections x 24 (17 used + pad)

typedef short bf16x8 __attribute__((ext_vector_type(8)));
typedef short bf16x4 __attribute__((ext_vector_type(4)));
typedef float f32x4 __attribute__((ext_vector_type(4)));

__device__ __forceinline__ float silu_f(float x) {
    return x / (1.0f + __expf(-x));
}
__device__ __forceinline__ float bf2f(short s) {
    union { unsigned u; float f; } c; c.u = (unsigned)(unsigned short)s << 16; return c.f;
}

// ---------------- weight reorder bodies (q-major i-mapping) ----------------
__device__ __forceinline__ void w2_body(
        int idx, const float* __restrict__ Wsrc,
        __hip_bfloat16* __restrict__ Whi, __hip_bfloat16* __restrict__ Wlo) {
    int l = idx >> 15;
    int rem = idx & 32767;
    int kk = rem >> 11;
    int nt = (rem >> 9) & 3;
    int c  = (rem >> 5) & 15;
    int q  = (rem >> 3) & 3;
    int j  = rem & 7;
    int i = q * 16 + kk;
    int k = nt * 16 + c;
    float wv = Wsrc[(size_t)l * 32768 + i * 512 + j * 64 + k];
    __hip_bfloat16 hi = __float2bfloat16(wv);
    Whi[idx] = hi;
    Wlo[idx] = __float2bfloat16(wv - __bfloat162float(hi));
}

__device__ __forceinline__ void w2h_body(
        int idx, const float* __restrict__ Wsrc, __hip_bfloat16* __restrict__ Whi) {
    int l = idx >> 15;
    int rem = idx & 32767;
    int kk = rem >> 11;
    int nt = (rem >> 9) & 3;
    int c  = (rem >> 5) & 15;
    int q  = (rem >> 3) & 3;
    int j  = rem & 7;
    int i = q * 16 + kk;
    int k = nt * 16 + c;
    Whi[idx] = __float2bfloat16(Wsrc[(size_t)l * 32768 + i * 512 + j * 64 + k]);
}

__device__ __forceinline__ void wu1_body(
        int idx, const float* __restrict__ Wu1,
        __hip_bfloat16* __restrict__ Whi, __hip_bfloat16* __restrict__ Wlo) {
    int l = idx / 67584;
    int rem = idx % 67584;
    int kk = rem / 2048;          // 0..32
    int r2 = rem % 2048;
    int nt = (r2 >> 9) & 3;
    int c  = (r2 >> 5) & 15;
    int q  = (r2 >> 3) & 3;
    int j  = r2 & 7;
    int i = q * 33 + kk;          // 0..131
    float wv = (i < 129) ? Wu1[(size_t)l * 129 * 512 + i * 512 + j * 64 + nt * 16 + c] : 0.f;
    __hip_bfloat16 hi = __float2bfloat16(wv);
    Whi[idx] = hi;
    Wlo[idx] = __float2bfloat16(wv - __bfloat162float(hi));
}

__device__ __forceinline__ void wm1z_body(
        int idx, const float* __restrict__ Wm1, __hip_bfloat16* __restrict__ Whi) {
    int l = idx / 71680;
    int rem = idx % 71680;
    int kkn = rem >> 9;          // 0..139
    int off = rem & 511;
    int kk = kkn >> 2;
    int nt = kkn & 3;
    int c16 = off >> 5;
    int q = (off >> 3) & 3;
    int j = off & 7;
    int k = nt * 16 + c16;
    int wi = -1;
    if (kk < 17) { int i = q * 17 + kk; if (i <= 64) wi = i; }
    else if (kk < 34) { int s = q * 17 + (kk - 17); if (s <= 64) wi = 65 + s; }
    else { if (q == 0) wi = 130; }
    float wv = (wi >= 0) ? Wm1[((size_t)l * 131 + wi) * 512 + j * 64 + k] : 0.f;
    Whi[idx] = __float2bfloat16(wv);
}

// ---------------- mega pre-kernel: all weight reorders + hist zero + embed ----------------
constexpr int PB_W2H  = 0;                 // 256 blocks: Wm2 -> W2hi
constexpr int PB_WM1Z = PB_W2H  + 256;     // 560
constexpr int PB_WU1  = PB_WM1Z + 560;     // 528
constexpr int PB_WU2  = PB_WU1  + 528;     // 256
constexpr int PB_WP1  = PB_WU2  + 256;     // 128
constexpr int PB_WP2  = PB_WP1  + 128;     // 128
constexpr int PB_ZERO = PB_WP2  + 128;     // 40
constexpr int PB_EMB  = PB_ZERO + 40;      // 625
constexpr int PB_TOTAL= PB_EMB  + 625;     // 2521

__global__ __launch_bounds__(256) void k_pre(
        const float* __restrict__ Wm2, __hip_bfloat16* __restrict__ W2hi,
        const float* __restrict__ Wm1, __hip_bfloat16* __restrict__ Wm1zhi,
        const float* __restrict__ Wu1w, __hip_bfloat16* __restrict__ Wu1hi, __hip_bfloat16* __restrict__ Wu1lo,
        const float* __restrict__ Wu2w, __hip_bfloat16* __restrict__ Wu2hi, __hip_bfloat16* __restrict__ Wu2lo,
        const float* __restrict__ Wp1w, __hip_bfloat16* __restrict__ Wp1hi, __hip_bfloat16* __restrict__ Wp1lo,
        const float* __restrict__ Wp2w, __hip_bfloat16* __restrict__ Wp2hi, __hip_bfloat16* __restrict__ Wp2lo,
        int* __restrict__ hist,
        const float* __restrict__ x, const float* __restrict__ anf,
        const float* __restrict__ na, const float* __restrict__ W_emb,
        const float* __restrict__ b_emb,
        float* __restrict__ h, __hip_bfloat16* __restrict__ hb, float* __restrict__ agg) {
    __shared__ float xs[16][18];
    __shared__ float na_s[16][8];
    int tid = threadIdx.x;
    int bx = blockIdx.x;
    if (bx < PB_WM1Z) {
        w2h_body((bx - PB_W2H) * 256 + tid, Wm2, W2hi);
    } else if (bx < PB_WU1) {
        wm1z_body((bx - PB_WM1Z) * 256 + tid, Wm1, Wm1zhi);
    } else if (bx < PB_WU2) {
        wu1_body((bx - PB_WU1) * 256 + tid, Wu1w, Wu1hi, Wu1lo);
    } else if (bx < PB_WP1) {
        w2_body((bx - PB_WU2) * 256 + tid, Wu2w, Wu2hi, Wu2lo);
    } else if (bx < PB_WP2) {
        w2_body((bx - PB_WP1) * 256 + tid, Wp1w, Wp1hi, Wp1lo);
    } else if (bx < PB_ZERO) {
        w2_body((bx - PB_WP2) * 256 + tid, Wp2w, Wp2hi, Wp2lo);
    } else if (bx < PB_EMB) {
        int i = (bx - PB_ZERO) * 256 + tid;
        if (i < N) hist[i] = 0;
    } else {
        // ---- embed: h fp32 + hb (q-sectioned) + agg zero ----
        int eb = bx - PB_EMB;
        int w = tid >> 6, l = tid & 63;
        int n0 = eb * 16;
        {
            int r = tid >> 4, c = tid & 15;
            xs[r][c] = x[(size_t)(n0 + r) * 16 + c];
        }
        if (tid < 16) xs[tid][16] = anf[n0 + tid];
        if (tid < 128) na_s[tid >> 3][tid & 7] = na[(size_t)n0 * 8 + tid];
        float4 z4 = {0.f, 0.f, 0.f, 0.f};
        ((float4*)(agg + (size_t)eb * 1024))[tid] = z4;
        for (int t = tid; t < 192; t += 256)
            ((float4*)(hb + (size_t)n0 * HS))[t] = z4;
        __syncthreads();
        float acc[4];
#pragma unroll
        for (int t = 0; t < 4; ++t) acc[t] = b_emb[l];
        for (int i = 0; i < 17; ++i) {
#pragma unroll
            for (int j = 0; j < 8; ++j) {
                float wv = W_emb[(i * 8 + j) * 64 + l];
#pragma unroll
                for (int t = 0; t < 4; ++t) {
                    int nn = w * 4 + t;
                    acc[t] = fmaf(xs[nn][i] * na_s[nn][j], wv, acc[t]);
                }
            }
        }
        int slot = (l / 17) * 24 + l % 17;
#pragma unroll
        for (int t = 0; t < 4; ++t) {
            int n = n0 + w * 4 + t;
            h[(size_t)n * 64 + l] = acc[t];
            hb[(size_t)n * HS + slot] = __float2bfloat16(acc[t]);
        }
        if (tid < 16) hb[(size_t)(n0 + tid) * HS + 85] = __float2bfloat16(xs[tid][16]);
    }
}

// ---------------- edge sort by dst: histogram / scan / scatter+materialize ----------------
__global__ __launch_bounds__(256) void k_hist(
        const int* __restrict__ eidx, int* __restrict__ hist) {
    int e = blockIdx.x * 256 + threadIdx.x;
    if (e < E) atomicAdd(&hist[eidx[E + e]], 1);
}

// single-block exclusive scan over N=10000 bins -> cursor
__global__ __launch_bounds__(1024) void k_scan(
        const int* __restrict__ hist, int* __restrict__ cursor) {
    __shared__ int wsum[16];
    int t = threadIdx.x;
    int base = t * 10;
    int loc[10];
    int s = 0;
#pragma unroll
    for (int i = 0; i < 10; ++i) {
        int v = (base + i < N) ? hist[base + i] : 0;
        loc[i] = s;
        s += v;
    }
    int lane = t & 63, w = t >> 6;
    int incl = s;
    for (int off = 1; off < 64; off <<= 1) {
        int u = __shfl_up(incl, off, 64);
        if (lane >= off) incl += u;
    }
    if (lane == 63) wsum[w] = incl;
    __syncthreads();
    if (t == 0) {
        int a = 0;
        for (int i2 = 0; i2 < 16; ++i2) { int v = wsum[i2]; wsum[i2] = a; a += v; }
    }
    __syncthreads();
    int excl = incl - s + wsum[w];
#pragma unroll
    for (int i = 0; i < 10; ++i) {
        int p = base + i;
        if (p < N) cursor[p] = excl + loc[i];
    }
}

// scatter into dst-sorted records (coalesced reads; 48B record = 1-2 line touches/edge)
__global__ __launch_bounds__(256) void k_scatter_sort(
        const int* __restrict__ eidx, const float* __restrict__ ea,
        const float* __restrict__ amf, int* __restrict__ cursor,
        int* __restrict__ dstS, float4* __restrict__ recs) {
    int e = blockIdx.x * 256 + threadIdx.x;
    if (e < E) {
        int d = eidx[E + e];
        int p = atomicAdd(&cursor[d], 1);
        dstS[p] = d;
        float4 a0 = ((const float4*)ea)[(size_t)e * 2];
        float4 a1 = ((const float4*)ea)[(size_t)e * 2 + 1];
        float4 r0 = {__int_as_float(eidx[e]), amf[e], a0.x, a0.y};
        float4 r1 = {a0.z, a0.w, a1.x, a1.y};
        float4 r2 = {a1.z, a1.w, 0.f, 0.f};
        recs[(size_t)p * 3 + 0] = r0;
        recs[(size_t)p * 3 + 1] = r1;
        recs[(size_t)p * 3 + 2] = r2;
    }
}

// ---------------- device helper: one z-GEMM stage (hi/lo), 4 waves split K, q-major x ----------------
__device__ __forceinline__ void zgemm_stage(
        const __hip_bfloat16* xsrc, int xstride, int kkmax, int Lq,
        int w, int c16, int q, int lofs, const float* naA,
        const __hip_bfloat16* __restrict__ Whi, const __hip_bfloat16* __restrict__ Wlo,
        float (*part_s)[16][64]) {
    f32x4 zero4 = {0.f, 0.f, 0.f, 0.f};
    f32x4 acc[4];
#pragma unroll
    for (int nt = 0; nt < 4; ++nt) acc[nt] = zero4;
    for (int kk = w; kk < kkmax; kk += 4) {
        bf16x8 bh[4], bl[4];
#pragma unroll
        for (int nt = 0; nt < 4; ++nt) {
            int off = (kk * 4 + nt) * 512 + lofs;
            bh[nt] = *(const bf16x8*)(Whi + off);
            bl[nt] = *(const bf16x8*)(Wlo + off);
        }
        float mv = __bfloat162float(xsrc[c16 * xstride + q * Lq + kk]);
        union { bf16x8 v; __hip_bfloat16 hx[8]; } au;
#pragma unroll
        for (int j = 0; j < 8; ++j) au.hx[j] = __float2bfloat16(mv * naA[j]);
#pragma unroll
        for (int nt = 0; nt < 4; ++nt) {
            acc[nt] = __builtin_amdgcn_mfma_f32_16x16x32_bf16(au.v, bh[nt], acc[nt], 0, 0, 0);
            acc[nt] = __builtin_amdgcn_mfma_f32_16x16x32_bf16(au.v, bl[nt], acc[nt], 0, 0, 0);
        }
    }
#pragma unroll
    for (int nt = 0; nt < 4; ++nt)
#pragma unroll
        for (int r = 0; r < 4; ++r) part_s[w][q * 4 + r][nt * 16 + c16] = acc[nt][r];
}

// ---------------- K3: edge kernel — wave-private LDS, zero barriers ----------------
// launch_bounds 256 + amdgpu_waves_per_eu(4,4): the r4 kernel compiled to 64 VGPR because
// LLVM opportunistically targets 8 waves/EU when only a MIN waves bound is given — leaving
// ~1 weight chunk in flight (latency-bound: all counters <34%, r4). Pinning max=min=4
// unlocks the full 128-VGPR budget so the scheduler hoists weight loads itself (what r5's
// manual ring failed to force; r5's barriers also destroyed wave skew — keep zero barriers).
// NOT 8 waves/EU floor: unified VGPR/AGPR file -> total spill (r3). Occupancy can't regress:
// hard cap 16 waves/CU vs ~11 measured (grid-limited at 4.9 blocks/CU).
__global__ __launch_bounds__(256) __attribute__((amdgpu_waves_per_eu(4, 4))) void k_edge(
        const float4* __restrict__ recs, const int* __restrict__ dstS,
        const __hip_bfloat16* __restrict__ hb,
        const __hip_bfloat16* __restrict__ W1hi, const float* __restrict__ bm1_l,
        const __hip_bfloat16* __restrict__ W2hi,
        const float* __restrict__ bm2_l, float* __restrict__ agg) {
    // per-wave private 4608B region: m_s [32][72] bf16; m2 chunk [16][66] f32 overlaid
    __shared__ __align__(16) char smem_u[4 * 4608];   // 18432 B
    __shared__ int dst_s[128];
    int tid = threadIdx.x;
    int l = tid & 63, w = tid >> 6;
    int e0 = blockIdx.x * 128;
    __hip_bfloat16* m_s = (__hip_bfloat16*)(smem_u + w * 4608);
    float* m2 = (float*)(smem_u + w * 4608);

    if (l < 32) dst_s[w * 32 + l] = dstS[e0 + w * 32 + l];   // wave-private write+read

    int c16 = l & 15, q = l >> 4;
    int e0w = w * 32;
    float eaA[2][8], amfA[2];
    int dL[2], sL[2];
#pragma unroll
    for (int mt = 0; mt < 2; ++mt) {
        int e = e0 + e0w + mt * 16 + c16;
        float4 r0 = recs[(size_t)e * 3];
        float4 r1 = recs[(size_t)e * 3 + 1];
        float4 r2 = recs[(size_t)e * 3 + 2];
        sL[mt] = __float_as_int(r0.x);
        amfA[mt] = r0.y;
        eaA[mt][0] = r0.z; eaA[mt][1] = r0.w;
        eaA[mt][2] = r1.x; eaA[mt][3] = r1.y; eaA[mt][4] = r1.z; eaA[mt][5] = r1.w;
        eaA[mt][6] = r2.x; eaA[mt][7] = r2.y;
        dL[mt] = dstS[e];
    }
    float bR1[4], bR2[4];
#pragma unroll
    for (int nt = 0; nt < 4; ++nt) {
        bR1[nt] = bm1_l[nt * 16 + c16];
        bR2[nt] = bm2_l[nt * 16 + c16];
    }
    int lofs = (c16 * 4 + q) * 8;
    f32x4 zero4 = {0.f, 0.f, 0.f, 0.f};

    bf16x4 xD[2][5], xS[2][5];
#pragma unroll
    for (int mt = 0; mt < 2; ++mt) {
        const __hip_bfloat16* bd = hb + (size_t)dL[mt] * HS + q * 24;
        const __hip_bfloat16* bs = hb + (size_t)sL[mt] * HS + q * 24;
#pragma unroll
        for (int t = 0; t < 5; ++t) {
            xD[mt][t] = *(const bf16x4*)(bd + t * 4);
            xS[mt][t] = *(const bf16x4*)(bs + t * 4);
        }
    }

    // phase 1
    f32x4 acc1[2][4];
#pragma unroll
    for (int mt = 0; mt < 2; ++mt)
#pragma unroll
        for (int nt = 0; nt < 4; ++nt) acc1[mt][nt] = zero4;
#pragma unroll
    for (int kk = 0; kk < 17; ++kk) {
        bf16x8 bh[4];
#pragma unroll
        for (int nt = 0; nt < 4; ++nt)
            bh[nt] = *(const bf16x8*)(W1hi + (kk * 4 + nt) * 512 + lofs);
#pragma unroll
        for (int mt = 0; mt < 2; ++mt) {
            float xv = bf2f(xD[mt][kk >> 2][kk & 3]);
            union { bf16x8 v; __hip_bfloat16 hx[8]; } au;
#pragma unroll
            for (int j = 0; j < 8; ++j) au.hx[j] = __float2bfloat16(xv * eaA[mt][j]);
#pragma unroll
            for (int nt = 0; nt < 4; ++nt)
                acc1[mt][nt] = __builtin_amdgcn_mfma_f32_16x16x32_bf16(au.v, bh[nt], acc1[mt][nt], 0, 0, 0);
        }
    }
#pragma unroll
    for (int kk = 0; kk < 17; ++kk) {
        bf16x8 bh[4];
#pragma unroll
        for (int nt = 0; nt < 4; ++nt)
            bh[nt] = *(const bf16x8*)(W1hi + ((17 + kk) * 4 + nt) * 512 + lofs);
#pragma unroll
        for (int mt = 0; mt < 2; ++mt) {
            float xv = bf2f(xS[mt][kk >> 2][kk & 3]);
            union { bf16x8 v; __hip_bfloat16 hx[8]; } au;
#pragma unroll
            for (int j = 0; j < 8; ++j) au.hx[j] = __float2bfloat16(xv * eaA[mt][j]);
#pragma unroll
            for (int nt = 0; nt < 4; ++nt)
                acc1[mt][nt] = __builtin_amdgcn_mfma_f32_16x16x32_bf16(au.v, bh[nt], acc1[mt][nt], 0, 0, 0);
        }
    }
    {   // amf chunk
        bf16x8 bh[4];
#pragma unroll
        for (int nt = 0; nt < 4; ++nt)
            bh[nt] = *(const bf16x8*)(W1hi + (34 * 4 + nt) * 512 + lofs);
#pragma unroll
        for (int mt = 0; mt < 2; ++mt) {
            float xv = (q == 0) ? amfA[mt] : 0.f;
            union { bf16x8 v; __hip_bfloat16 hx[8]; } au;
#pragma unroll
            for (int j = 0; j < 8; ++j) au.hx[j] = __float2bfloat16(xv * eaA[mt][j]);
#pragma unroll
            for (int nt = 0; nt < 4; ++nt)
                acc1[mt][nt] = __builtin_amdgcn_mfma_f32_16x16x32_bf16(au.v, bh[nt], acc1[mt][nt], 0, 0, 0);
        }
    }
    // stage m (wave-local rows 0..31) — no barrier needed anywhere in this kernel
#pragma unroll
    for (int mt = 0; mt < 2; ++mt)
#pragma unroll
        for (int nt = 0; nt < 4; ++nt) {
            int kd = nt * 16 + c16;
            float bias = bR1[nt];
#pragma unroll
            for (int r = 0; r < 4; ++r) {
                int el = mt * 16 + q * 4 + r;
                m_s[el * MS + kd] = __float2bfloat16(silu_f(bias + acc1[mt][nt][r]));
            }
        }

    // phase 2 (hi-only): read transposed m fragments
    bf16x4 mR[2][4];
#pragma unroll
    for (int mt = 0; mt < 2; ++mt)
#pragma unroll
        for (int t = 0; t < 4; ++t)
            mR[mt][t] = *(const bf16x4*)&m_s[(mt * 16 + c16) * MS + q * 16 + t * 4];

    // compiler barrier: m2 (float) writes below alias m_s (bf16) bytes — forbid TBAA reordering
    asm volatile("" ::: "memory");

    f32x4 acc[2][4];
#pragma unroll
    for (int mt = 0; mt < 2; ++mt)
#pragma unroll
        for (int nt = 0; nt < 4; ++nt) acc[mt][nt] = zero4;
#pragma unroll
    for (int kk = 0; kk < 16; ++kk) {
        bf16x8 bh[4];
#pragma unroll
        for (int nt = 0; nt < 4; ++nt)
            bh[nt] = *(const bf16x8*)(W2hi + (kk * 4 + nt) * 512 + lofs);
#pragma unroll
        for (int mt = 0; mt < 2; ++mt) {
            float mv = bf2f(mR[mt][kk >> 2][kk & 3]);
            union { bf16x8 v; __hip_bfloat16 h[8]; } au;
#pragma unroll
            for (int j = 0; j < 8; ++j) au.h[j] = __float2bfloat16(mv * eaA[mt][j]);
#pragma unroll
            for (int nt = 0; nt < 4; ++nt)
                acc[mt][nt] = __builtin_amdgcn_mfma_f32_16x16x32_bf16(au.v, bh[nt], acc[mt][nt], 0, 0, 0);
        }
    }

    // chunked epilogue: per mt-chunk write 16 rows of m2 (own region), run-length reduce, atomics.
    // runs spanning chunk boundaries just produce one extra atomic — still exact.
#pragma unroll
    for (int mt = 0; mt < 2; ++mt) {
#pragma unroll
        for (int nt = 0; nt < 4; ++nt) {
            int kd = nt * 16 + c16;
            float bias = bR2[nt];
#pragma unroll
            for (int r = 0; r < 4; ++r)
                m2[(q * 4 + r) * 66 + kd] = silu_f(bias + acc[mt][nt][r]);
        }
        int rb = w * 32 + mt * 16;
        float run = 0.f;
        int cur_d = dst_s[rb];
        for (int i = 0; i < 16; ++i) {
            int d = dst_s[rb + i];                 // wave-uniform
            if (d != cur_d) {
                atomicAdd(&agg[(size_t)cur_d * 64 + l], run);
                run = 0.f;
                cur_d = d;
            }
            run += m2[i * 66 + l];
        }
        atomicAdd(&agg[(size_t)cur_d * 64 + l], run);
        asm volatile("" ::: "memory");             // chunk reads complete before next chunk overwrite
    }
}

// ---------------- K4: node update + write h/hb + agg zero ----------------
__global__ __launch_bounds__(256) void k_upd_hb(
        const float* __restrict__ h_in, const float* __restrict__ anf,
        const float* __restrict__ na, const float* __restrict__ agg_in,
        const __hip_bfloat16* __restrict__ W1hi, const __hip_bfloat16* __restrict__ W1lo,
        const float* __restrict__ bu1_l,
        const __hip_bfloat16* __restrict__ W2hi_, const __hip_bfloat16* __restrict__ W2lo_,
        const float* __restrict__ bu2_l,
        float* __restrict__ h, __hip_bfloat16* __restrict__ hb, float* __restrict__ agg) {
    __shared__ __align__(16) __hip_bfloat16 xa_s[16 * 136];
    __shared__ __align__(16) __hip_bfloat16 u1_s[16 * 72];
    __shared__ float part_s[4][16][64];
    int tid = threadIdx.x;
    int w = tid >> 6, l = tid & 63;
    int n0 = blockIdx.x * 16;
    for (int idx = tid; idx < 16 * 132; idx += 256) {
        int r = idx / 132, c = idx % 132;
        int n = n0 + r;
        float v;
        if (c < 64) v = h_in[(size_t)n * 64 + c];
        else if (c == 64) v = anf[n];
        else if (c < 129) v = agg_in[(size_t)n * 64 + (c - 65)];
        else v = 0.f;
        xa_s[r * 136 + c] = __float2bfloat16(v);
    }
    int c16 = l & 15, q = l >> 4;
    float naA[8];
#pragma unroll
    for (int j = 0; j < 8; ++j) naA[j] = na[(size_t)(n0 + c16) * 8 + j];
    __syncthreads();
    float4 z4 = {0.f, 0.f, 0.f, 0.f};
    ((float4*)(agg + (size_t)blockIdx.x * 1024))[tid] = z4;
    for (int t = tid; t < 192; t += 256)
        ((float4*)(hb + (size_t)n0 * HS))[t] = z4;
    int lofs = (c16 * 4 + q) * 8;
    zgemm_stage(xa_s, 136, 33, 33, w, c16, q, lofs, naA, W1hi, W1lo, part_s);
    __syncthreads();
    for (int t = tid; t < 1024; t += 256) {
        int row = t >> 6, col = t & 63;
        float v = part_s[0][row][col] + part_s[1][row][col] + part_s[2][row][col] +
                  part_s[3][row][col] + bu1_l[col];
        u1_s[row * 72 + col] = __float2bfloat16(silu_f(v));
    }
    __syncthreads();
    zgemm_stage(u1_s, 72, 16, 16, w, c16, q, lofs, naA, W2hi_, W2lo_, part_s);
    __syncthreads();
    for (int t = tid; t < 1024; t += 256) {
        int row = t >> 6, col = t & 63;
        float v = part_s[0][row][col] + part_s[1][row][col] + part_s[2][row][col] +
                  part_s[3][row][col] + bu2_l[col];
        int n = n0 + row;
        float hn = h[(size_t)n * 64 + col] + v;
        h[(size_t)n * 64 + col] = hn;
        hb[(size_t)n * HS + (col / 17) * 24 + col % 17] = __float2bfloat16(hn);
    }
    if (tid < 16) hb[(size_t)(n0 + tid) * HS + 85] = __float2bfloat16(anf[n0 + tid]);
}

// ---------------- K6: fused node update (layer 1) + prepool -> p2 ----------------
__global__ __launch_bounds__(256) void k_upd_prepool(
        const float* __restrict__ h_in, const float* __restrict__ anf,
        const float* __restrict__ na, const float* __restrict__ agg_in,
        const __hip_bfloat16* __restrict__ W1hi, const __hip_bfloat16* __restrict__ W1lo,
        const float* __restrict__ bu1_l,
        const __hip_bfloat16* __restrict__ W2hi_, const __hip_bfloat16* __restrict__ W2lo_,
        const float* __restrict__ bu2_l,
        const __hip_bfloat16* __restrict__ Wp1hi, const __hip_bfloat16* __restrict__ Wp1lo,
        const float* __restrict__ bp1,
        const __hip_bfloat16* __restrict__ Wp2hi, const __hip_bfloat16* __restrict__ Wp2lo,
        const float* __restrict__ bp2,
        float* __restrict__ p2) {
    __shared__ __align__(16) __hip_bfloat16 xa_s[16 * 136];
    __shared__ __align__(16) __hip_bfloat16 u1_s[16 * 72];
    __shared__ __align__(16) __hip_bfloat16 x2_s[16 * 72];
    __shared__ float part_s[4][16][64];
    int tid = threadIdx.x;
    int w = tid >> 6, l = tid & 63;
    int n0 = blockIdx.x * 16;
    for (int idx = tid; idx < 16 * 132; idx += 256) {
        int r = idx / 132, c = idx % 132;
        int n = n0 + r;
        float v;
        if (c < 64) v = h_in[(size_t)n * 64 + c];
        else if (c == 64) v = anf[n];
        else if (c < 129) v = agg_in[(size_t)n * 64 + (c - 65)];
        else v = 0.f;
        xa_s[r * 136 + c] = __float2bfloat16(v);
    }
    int c16 = l & 15, q = l >> 4;
    float naA[8];
#pragma unroll
    for (int j = 0; j < 8; ++j) naA[j] = na[(size_t)(n0 + c16) * 8 + j];
    __syncthreads();
    int lofs = (c16 * 4 + q) * 8;
    zgemm_stage(xa_s, 136, 33, 33, w, c16, q, lofs, naA, W1hi, W1lo, part_s);
    __syncthreads();
    for (int t = tid; t < 1024; t += 256) {
        int row = t >> 6, col = t & 63;
        float v = part_s[0][row][col] + part_s[1][row][col] + part_s[2][row][col] +
                  part_s[3][row][col] + bu1_l[col];
        u1_s[row * 72 + col] = __float2bfloat16(silu_f(v));
    }
    __syncthreads();
    zgemm_stage(u1_s, 72, 16, 16, w, c16, q, lofs, naA, W2hi_, W2lo_, part_s);
    __syncthreads();
    for (int t = tid; t < 1024; t += 256) {
        int row = t >> 6, col = t & 63;
        float v = part_s[0][row][col] + part_s[1][row][col] + part_s[2][row][col] +
                  part_s[3][row][col] + bu2_l[col];
        float hn = h_in[(size_t)(n0 + row) * 64 + col] + v;
        x2_s[row * 72 + col] = __float2bfloat16(hn);
    }
    __syncthreads();
    zgemm_stage(x2_s, 72, 16, 16, w, c16, q, lofs, naA, Wp1hi, Wp1lo, part_s);
    __syncthreads();
    for (int t = tid; t < 1024; t += 256) {
        int row = t >> 6, col = t & 63;
        float v = part_s[0][row][col] + part_s[1][row][col] + part_s[2][row][col] +
                  part_s[3][row][col] + bp1[col];
        u1_s[row * 72 + col] = __float2bfloat16(silu_f(v));
    }
    __syncthreads();
    zgemm_stage(u1_s, 72, 16, 16, w, c16, q, lofs, naA, Wp2hi, Wp2lo, part_s);
    __syncthreads();
    for (int t = tid; t < 1024; t += 256) {
        int row = t >> 6, col = t & 63;
        float v = part_s[0][row][col] + part_s[1][row][col] + part_s[2][row][col] +
                  part_s[3][row][col] + bp2[col];
        p2[(size_t)(n0 + row) * 64 + col] = v;
    }
}

// ---------------- K_pool ----------------
__global__ __launch_bounds__(256) void k_pool(
        const float* __restrict__ p2, const int* __restrict__ batch,
        float* __restrict__ partial_p, float* __restrict__ partial_cnt) {
    __shared__ float acc_s[16 * 64];
    __shared__ float cnt_s[16];
    int tid = threadIdx.x;
    for (int idx = tid; idx < 1024; idx += 256) acc_s[idx] = 0.f;
    if (tid < 16) cnt_s[tid] = 0.f;
    __syncthreads();
    int w = tid >> 6, k = tid & 63;
    int base = blockIdx.x * 125;
    for (int i = 0; i < 32; ++i) {
        int nl = i * 4 + w;
        if (nl < 125) {
            int n = base + nl;
            int b = batch[n];
            atomicAdd(&acc_s[b * 64 + k], p2[(size_t)n * 64 + k]);
            if (k == 0) atomicAdd(&cnt_s[b], 1.0f);
        }
    }
    __syncthreads();
    for (int idx = tid; idx < 1024; idx += 256)
        partial_p[(size_t)blockIdx.x * 1024 + idx] = acc_s[idx];
    if (tid < 16) partial_cnt[blockIdx.x * 16 + tid] = cnt_s[tid];
}

// ---------------- K7: reduce partials, mean, final MLP ----------------
__global__ __launch_bounds__(1024) void k_final(
        const float* __restrict__ partial_p, const float* __restrict__ partial_cnt,
        const float* __restrict__ Wq1, const float* __restrict__ bq1,
        const float* __restrict__ Wq2, const float* __restrict__ bq2,
        float* __restrict__ out) {
    __shared__ float g[16][64];
    int b = threadIdx.x >> 6, k = threadIdx.x & 63;
    float s = 0.f, cc = 0.f;
    for (int c = 0; c < POOL_CHUNKS; ++c) s += partial_p[(size_t)c * 1024 + b * 64 + k];
    for (int c = 0; c < POOL_CHUNKS; ++c) cc += partial_cnt[c * 16 + b];
    g[b][k] = s / fmaxf(cc, 1.0f);
    __syncthreads();
    float acc = bq1[k];
#pragma unroll
    for (int i = 0; i < 64; ++i) acc = fmaf(g[b][i], Wq1[i * 64 + k], acc);
    float v = silu_f(acc) * Wq2[k];
#pragma unroll
    for (int off = 32; off > 0; off >>= 1) v += __shfl_down(v, off, 64);
    if (k == 0) out[b] = v + bq2[0];
}

extern "C" void kernel_launch(void* const* d_in, const int* in_sizes, int n_in,
                              void* d_out, int out_size, void* d_ws, size_t ws_size,
                              hipStream_t stream) {
    const float* x    = (const float*)d_in[0];
    const int*   eidx = (const int*)  d_in[1];
    const float* ea   = (const float*)d_in[2];
    const float* na   = (const float*)d_in[3];
    const float* amf  = (const float*)d_in[4];
    const float* anf  = (const float*)d_in[5];
    const int*   batch= (const int*)  d_in[6];
    const float* W_emb= (const float*)d_in[7];
    const float* b_emb= (const float*)d_in[8];
    const float* Wm1  = (const float*)d_in[9];
    const float* bm1  = (const float*)d_in[10];
    const float* Wm2  = (const float*)d_in[11];
    const float* bm2  = (const float*)d_in[12];
    const float* Wu1  = (const float*)d_in[13];
    const float* bu1  = (const float*)d_in[14];
    const float* Wu2  = (const float*)d_in[15];
    const float* bu2  = (const float*)d_in[16];
    const float* Wp1  = (const float*)d_in[17];
    const float* bp1  = (const float*)d_in[18];
    const float* Wp2  = (const float*)d_in[19];
    const float* bp2  = (const float*)d_in[20];
    const float* Wq1  = (const float*)d_in[21];
    const float* bq1  = (const float*)d_in[22];
    const float* Wq2  = (const float*)d_in[23];
    const float* bq2  = (const float*)d_in[24];

    float* ws = (float*)d_ws;
    float* h      = ws;                            // N*64
    float* agg    = h + (size_t)N * 64;            // N*64
    float* p2     = agg + (size_t)N * 64;          // N*64
    float* part_p = p2 + (size_t)N * 64;           // 80*1024
    float* part_c = part_p + POOL_CHUNKS * 1024;   // 80*16
    float* fend   = part_c + POOL_CHUNKS * 16;
    __hip_bfloat16* hb     = (__hip_bfloat16*)fend;          // N*96
    __hip_bfloat16* W2hi   = hb + (size_t)N * HS;            // 2*32768
    __hip_bfloat16* Wm1zhi = W2hi + 65536;                   // 2*71680
    __hip_bfloat16* Wu1hi  = Wm1zhi + 143360;                // 2*67584
    __hip_bfloat16* Wu1lo  = Wu1hi + 135168;
    __hip_bfloat16* Wu2hi  = Wu1lo + 135168;                 // 2*32768
    __hip_bfloat16* Wu2lo  = Wu2hi + 65536;
    __hip_bfloat16* Wp1hi  = Wu2lo + 65536;                  // 32768
    __hip_bfloat16* Wp1lo  = Wp1hi + 32768;
    __hip_bfloat16* Wp2hi  = Wp1lo + 32768;
    __hip_bfloat16* Wp2lo  = Wp2hi + 32768;
    int* hist   = (int*)(Wp2lo + 32768);                     // N
    int* cursor = hist + N;                                  // N
    int* dstS   = cursor + N;                                // E
    float4* recs = (float4*)(dstS + E);                      // E * 3 float4 (48B/edge)

    // mega pre-kernel: all weight reorders + hist zero + embed(+agg/hb init)
    k_pre<<<PB_TOTAL, 256, 0, stream>>>(
        Wm2, W2hi, Wm1, Wm1zhi, Wu1, Wu1hi, Wu1lo, Wu2, Wu2hi, Wu2lo,
        Wp1, Wp1hi, Wp1lo, Wp2, Wp2hi, Wp2lo, hist,
        x, anf, na, W_emb, b_emb, h, hb, agg);

    // dst-sort + materialize sorted edge records (reused by both edge dispatches)
    k_hist<<<(E + 255) / 256, 256, 0, stream>>>(eidx, hist);
    k_scan<<<1, 1024, 0, stream>>>(hist, cursor);
    k_scatter_sort<<<(E + 255) / 256, 256, 0, stream>>>(eidx, ea, amf, cursor, dstS, recs);

    k_edge<<<E / 128, 256, 0, stream>>>(recs, dstS, hb,
                                        Wm1zhi, bm1, W2hi, bm2, agg);
    k_upd_hb<<<625, 256, 0, stream>>>(h, anf, na, agg,
                                      Wu1hi, Wu1lo, bu1,
                                      Wu2hi, Wu2lo, bu2,
                                      h, hb, agg);
    k_edge<<<E / 128, 256, 0, stream>>>(recs, dstS, hb,
                                        Wm1zhi + 71680, bm1 + 64,
                                        W2hi + 32768, bm2 + 64, agg);
    k_upd_prepool<<<625, 256, 0, stream>>>(h, anf, na, agg,
                                           Wu1hi + 67584, Wu1lo + 67584, bu1 + 64,
                                           Wu2hi + 32768, Wu2lo + 32768, bu2 + 64,
                                           Wp1hi, Wp1lo, bp1, Wp2hi, Wp2lo, bp2, p2);
    k_pool<<<POOL_CHUNKS, 256, 0, stream>>>(p2, batch, part_p, part_c);
    k_final<<<1, 1024, 0, stream>>>(part_p, part_c, Wq1, bq1, Wq2, bq2, (float*)d_out);
}

// Round 7
// 373.249 us; speedup vs baseline: 1.0411x; 1.0185x over previous
//
#include <hip/hip_runtime.h>
#include <hip/hip_bf16.h>
#include <math.h>

// Problem constants
constexpr int N = 10000;
constexpr int E = 160000;
constexpr int B = 16;
constexpr int POOL_CHUNKS = 80;   // 80 * 125 = 10000
constexpr int MS = 72;            // m_s row stride (bf16), wave-local
constexpr int HS = 96;            // hb row stride: 4 q-sections x 24 (17 used + pad)

typedef short bf16x8 __attribute__((ext_vector_type(8)));
typedef short bf16x4 __attribute__((ext_vector_type(4)));
typedef float f32x4 __attribute__((ext_vector_type(4)));

__device__ __forceinline__ float silu_f(float x) {
    return x / (1.0f + __expf(-x));
}
__device__ __forceinline__ float bf2f(short s) {
    union { unsigned u; float f; } c; c.u = (unsigned)(unsigned short)s << 16; return c.f;
}

// ---------------- weight reorder bodies (q-major i-mapping) ----------------
__device__ __forceinline__ void w2_body(
        int idx, const float* __restrict__ Wsrc,
        __hip_bfloat16* __restrict__ Whi, __hip_bfloat16* __restrict__ Wlo) {
    int l = idx >> 15;
    int rem = idx & 32767;
    int kk = rem >> 11;
    int nt = (rem >> 9) & 3;
    int c  = (rem >> 5) & 15;
    int q  = (rem >> 3) & 3;
    int j  = rem & 7;
    int i = q * 16 + kk;
    int k = nt * 16 + c;
    float wv = Wsrc[(size_t)l * 32768 + i * 512 + j * 64 + k];
    __hip_bfloat16 hi = __float2bfloat16(wv);
    Whi[idx] = hi;
    Wlo[idx] = __float2bfloat16(wv - __bfloat162float(hi));
}

__device__ __forceinline__ void w2h_body(
        int idx, const float* __restrict__ Wsrc, __hip_bfloat16* __restrict__ Whi) {
    int l = idx >> 15;
    int rem = idx & 32767;
    int kk = rem >> 11;
    int nt = (rem >> 9) & 3;
    int c  = (rem >> 5) & 15;
    int q  = (rem >> 3) & 3;
    int j  = rem & 7;
    int i = q * 16 + kk;
    int k = nt * 16 + c;
    Whi[idx] = __float2bfloat16(Wsrc[(size_t)l * 32768 + i * 512 + j * 64 + k]);
}

__device__ __forceinline__ void wu1_body(
        int idx, const float* __restrict__ Wu1,
        __hip_bfloat16* __restrict__ Whi, __hip_bfloat16* __restrict__ Wlo) {
    int l = idx / 67584;
    int rem = idx % 67584;
    int kk = rem / 2048;          // 0..32
    int r2 = rem % 2048;
    int nt = (r2 >> 9) & 3;
    int c  = (r2 >> 5) & 15;
    int q  = (r2 >> 3) & 3;
    int j  = r2 & 7;
    int i = q * 33 + kk;          // 0..131
    float wv = (i < 129) ? Wu1[(size_t)l * 129 * 512 + i * 512 + j * 64 + nt * 16 + c] : 0.f;
    __hip_bfloat16 hi = __float2bfloat16(wv);
    Whi[idx] = hi;
    Wlo[idx] = __float2bfloat16(wv - __bfloat162float(hi));
}

__device__ __forceinline__ void wm1z_body(
        int idx, const float* __restrict__ Wm1, __hip_bfloat16* __restrict__ Whi) {
    int l = idx / 71680;
    int rem = idx % 71680;
    int kkn = rem >> 9;          // 0..139
    int off = rem & 511;
    int kk = kkn >> 2;
    int nt = kkn & 3;
    int c16 = off >> 5;
    int q = (off >> 3) & 3;
    int j = off & 7;
    int k = nt * 16 + c16;
    int wi = -1;
    if (kk < 17) { int i = q * 17 + kk; if (i <= 64) wi = i; }
    else if (kk < 34) { int s = q * 17 + (kk - 17); if (s <= 64) wi = 65 + s; }
    else { if (q == 0) wi = 130; }
    float wv = (wi >= 0) ? Wm1[((size_t)l * 131 + wi) * 512 + j * 64 + k] : 0.f;
    Whi[idx] = __float2bfloat16(wv);
}

// ---------------- mega pre-kernel: all weight reorders + hist zero + embed ----------------
constexpr int PB_W2H  = 0;                 // 256 blocks: Wm2 -> W2hi
constexpr int PB_WM1Z = PB_W2H  + 256;     // 560
constexpr int PB_WU1  = PB_WM1Z + 560;     // 528
constexpr int PB_WU2  = PB_WU1  + 528;     // 256
constexpr int PB_WP1  = PB_WU2  + 256;     // 128
constexpr int PB_WP2  = PB_WP1  + 128;     // 128
constexpr int PB_ZERO = PB_WP2  + 128;     // 40
constexpr int PB_EMB  = PB_ZERO + 40;      // 625
constexpr int PB_TOTAL= PB_EMB  + 625;     // 2521

__global__ __launch_bounds__(256) void k_pre(
        const float* __restrict__ Wm2, __hip_bfloat16* __restrict__ W2hi,
        const float* __restrict__ Wm1, __hip_bfloat16* __restrict__ Wm1zhi,
        const float* __restrict__ Wu1w, __hip_bfloat16* __restrict__ Wu1hi, __hip_bfloat16* __restrict__ Wu1lo,
        const float* __restrict__ Wu2w, __hip_bfloat16* __restrict__ Wu2hi, __hip_bfloat16* __restrict__ Wu2lo,
        const float* __restrict__ Wp1w, __hip_bfloat16* __restrict__ Wp1hi, __hip_bfloat16* __restrict__ Wp1lo,
        const float* __restrict__ Wp2w, __hip_bfloat16* __restrict__ Wp2hi, __hip_bfloat16* __restrict__ Wp2lo,
        int* __restrict__ hist,
        const float* __restrict__ x, const float* __restrict__ anf,
        const float* __restrict__ na, const float* __restrict__ W_emb,
        const float* __restrict__ b_emb,
        float* __restrict__ h, __hip_bfloat16* __restrict__ hb, float* __restrict__ agg) {
    __shared__ float xs[16][18];
    __shared__ float na_s[16][8];
    int tid = threadIdx.x;
    int bx = blockIdx.x;
    if (bx < PB_WM1Z) {
        w2h_body((bx - PB_W2H) * 256 + tid, Wm2, W2hi);
    } else if (bx < PB_WU1) {
        wm1z_body((bx - PB_WM1Z) * 256 + tid, Wm1, Wm1zhi);
    } else if (bx < PB_WU2) {
        wu1_body((bx - PB_WU1) * 256 + tid, Wu1w, Wu1hi, Wu1lo);
    } else if (bx < PB_WP1) {
        w2_body((bx - PB_WU2) * 256 + tid, Wu2w, Wu2hi, Wu2lo);
    } else if (bx < PB_WP2) {
        w2_body((bx - PB_WP1) * 256 + tid, Wp1w, Wp1hi, Wp1lo);
    } else if (bx < PB_ZERO) {
        w2_body((bx - PB_WP2) * 256 + tid, Wp2w, Wp2hi, Wp2lo);
    } else if (bx < PB_EMB) {
        int i = (bx - PB_ZERO) * 256 + tid;
        if (i < N) hist[i] = 0;
    } else {
        // ---- embed: h fp32 + hb (q-sectioned) + agg zero ----
        int eb = bx - PB_EMB;
        int w = tid >> 6, l = tid & 63;
        int n0 = eb * 16;
        {
            int r = tid >> 4, c = tid & 15;
            xs[r][c] = x[(size_t)(n0 + r) * 16 + c];
        }
        if (tid < 16) xs[tid][16] = anf[n0 + tid];
        if (tid < 128) na_s[tid >> 3][tid & 7] = na[(size_t)n0 * 8 + tid];
        float4 z4 = {0.f, 0.f, 0.f, 0.f};
        ((float4*)(agg + (size_t)eb * 1024))[tid] = z4;
        for (int t = tid; t < 192; t += 256)
            ((float4*)(hb + (size_t)n0 * HS))[t] = z4;
        __syncthreads();
        float acc[4];
#pragma unroll
        for (int t = 0; t < 4; ++t) acc[t] = b_emb[l];
        for (int i = 0; i < 17; ++i) {
#pragma unroll
            for (int j = 0; j < 8; ++j) {
                float wv = W_emb[(i * 8 + j) * 64 + l];
#pragma unroll
                for (int t = 0; t < 4; ++t) {
                    int nn = w * 4 + t;
                    acc[t] = fmaf(xs[nn][i] * na_s[nn][j], wv, acc[t]);
                }
            }
        }
        int slot = (l / 17) * 24 + l % 17;
#pragma unroll
        for (int t = 0; t < 4; ++t) {
            int n = n0 + w * 4 + t;
            h[(size_t)n * 64 + l] = acc[t];
            hb[(size_t)n * HS + slot] = __float2bfloat16(acc[t]);
        }
        if (tid < 16) hb[(size_t)(n0 + tid) * HS + 85] = __float2bfloat16(xs[tid][16]);
    }
}

// ---------------- edge sort by dst: histogram / scan / scatter+materialize ----------------
__global__ __launch_bounds__(256) void k_hist(
        const int* __restrict__ eidx, int* __restrict__ hist) {
    int e = blockIdx.x * 256 + threadIdx.x;
    if (e < E) atomicAdd(&hist[eidx[E + e]], 1);
}

// single-block exclusive scan over N=10000 bins -> cursor
__global__ __launch_bounds__(1024) void k_scan(
        const int* __restrict__ hist, int* __restrict__ cursor) {
    __shared__ int wsum[16];
    int t = threadIdx.x;
    int base = t * 10;
    int loc[10];
    int s = 0;
#pragma unroll
    for (int i = 0; i < 10; ++i) {
        int v = (base + i < N) ? hist[base + i] : 0;
        loc[i] = s;
        s += v;
    }
    int lane = t & 63, w = t >> 6;
    int incl = s;
    for (int off = 1; off < 64; off <<= 1) {
        int u = __shfl_up(incl, off, 64);
        if (lane >= off) incl += u;
    }
    if (lane == 63) wsum[w] = incl;
    __syncthreads();
    if (t == 0) {
        int a = 0;
        for (int i2 = 0; i2 < 16; ++i2) { int v = wsum[i2]; wsum[i2] = a; a += v; }
    }
    __syncthreads();
    int excl = incl - s + wsum[w];
#pragma unroll
    for (int i = 0; i < 10; ++i) {
        int p = base + i;
        if (p < N) cursor[p] = excl + loc[i];
    }
}

// scatter into dst-sorted records (coalesced reads; 48B record = 1-2 line touches/edge)
__global__ __launch_bounds__(256) void k_scatter_sort(
        const int* __restrict__ eidx, const float* __restrict__ ea,
        const float* __restrict__ amf, int* __restrict__ cursor,
        int* __restrict__ dstS, float4* __restrict__ recs) {
    int e = blockIdx.x * 256 + threadIdx.x;
    if (e < E) {
        int d = eidx[E + e];
        int p = atomicAdd(&cursor[d], 1);
        dstS[p] = d;
        float4 a0 = ((const float4*)ea)[(size_t)e * 2];
        float4 a1 = ((const float4*)ea)[(size_t)e * 2 + 1];
        float4 r0 = {__int_as_float(eidx[e]), amf[e], a0.x, a0.y};
        float4 r1 = {a0.z, a0.w, a1.x, a1.y};
        float4 r2 = {a1.z, a1.w, 0.f, 0.f};
        recs[(size_t)p * 3 + 0] = r0;
        recs[(size_t)p * 3 + 1] = r1;
        recs[(size_t)p * 3 + 2] = r2;
    }
}

// ---------------- device helper: one z-GEMM stage (hi/lo), 4 waves split K, q-major x ----------------
__device__ __forceinline__ void zgemm_stage(
        const __hip_bfloat16* xsrc, int xstride, int kkmax, int Lq,
        int w, int c16, int q, int lofs, const float* naA,
        const __hip_bfloat16* __restrict__ Whi, const __hip_bfloat16* __restrict__ Wlo,
        float (*part_s)[16][64]) {
    f32x4 zero4 = {0.f, 0.f, 0.f, 0.f};
    f32x4 acc[4];
#pragma unroll
    for (int nt = 0; nt < 4; ++nt) acc[nt] = zero4;
    for (int kk = w; kk < kkmax; kk += 4) {
        bf16x8 bh[4], bl[4];
#pragma unroll
        for (int nt = 0; nt < 4; ++nt) {
            int off = (kk * 4 + nt) * 512 + lofs;
            bh[nt] = *(const bf16x8*)(Whi + off);
            bl[nt] = *(const bf16x8*)(Wlo + off);
        }
        float mv = __bfloat162float(xsrc[c16 * xstride + q * Lq + kk]);
        union { bf16x8 v; __hip_bfloat16 hx[8]; } au;
#pragma unroll
        for (int j = 0; j < 8; ++j) au.hx[j] = __float2bfloat16(mv * naA[j]);
#pragma unroll
        for (int nt = 0; nt < 4; ++nt) {
            acc[nt] = __builtin_amdgcn_mfma_f32_16x16x32_bf16(au.v, bh[nt], acc[nt], 0, 0, 0);
            acc[nt] = __builtin_amdgcn_mfma_f32_16x16x32_bf16(au.v, bl[nt], acc[nt], 0, 0, 0);
        }
    }
#pragma unroll
    for (int nt = 0; nt < 4; ++nt)
#pragma unroll
        for (int r = 0; r < 4; ++r) part_s[w][q * 4 + r][nt * 16 + c16] = acc[nt][r];
}

// ---------------- K3: edge kernel — LDS-staged weights (dbuf), one barrier/chunk ----------------
// r4-r6 established: per-wave ILP cannot be bought from the compiler (VGPR pins at ~60 under
// every hint; waves_per_eu(4,4) only capped occupancy, r6). The structural fix: the 4 waves
// of a block redundantly stream the SAME 204KB weight stream from L2 (816KB/block). Stage it
// in LDS once per block: 16KB chunks (4 kk-steps), double-buffered, reg-staged with loads
// issued BEFORE consuming the current chunk (latency hides under compute), ds_write after,
// one __syncthreads per chunk. L2 weight traffic /4; hot-loop loads become ds_read_b128.
// LDS 51.7KB -> 3 blocks/CU = 12 waves/CU ~= the measured 11 -> occupancy not regressed.
__global__ __launch_bounds__(256, 3) void k_edge(
        const float4* __restrict__ recs, const int* __restrict__ dstS,
        const __hip_bfloat16* __restrict__ hb,
        const __hip_bfloat16* __restrict__ W1hi, const float* __restrict__ bm1_l,
        const __hip_bfloat16* __restrict__ W2hi,
        const float* __restrict__ bm2_l, float* __restrict__ agg) {
    __shared__ __align__(16) __hip_bfloat16 wbuf[2][8192];   // 2 x 16KB weight chunks
    // per-wave private 4608B region: m_s [32][72] bf16; m2 chunk [16][66] f32 overlaid
    __shared__ __align__(16) char smem_u[4 * 4608];          // 18432 B
    __shared__ int dst_s[128];
    int tid = threadIdx.x;
    int l = tid & 63, w = tid >> 6;
    int e0 = blockIdx.x * 128;
    __hip_bfloat16* m_s = (__hip_bfloat16*)(smem_u + w * 4608);
    float* m2 = (float*)(smem_u + w * 4608);

    if (l < 32) dst_s[w * 32 + l] = dstS[e0 + w * 32 + l];

    int c16 = l & 15, q = l >> 4;
    int e0w = w * 32;
    float eaA[2][8], amfA[2];
    int dL[2], sL[2];
#pragma unroll
    for (int mt = 0; mt < 2; ++mt) {
        int e = e0 + e0w + mt * 16 + c16;
        float4 r0 = recs[(size_t)e * 3];
        float4 r1 = recs[(size_t)e * 3 + 1];
        float4 r2 = recs[(size_t)e * 3 + 2];
        sL[mt] = __float_as_int(r0.x);
        amfA[mt] = r0.y;
        eaA[mt][0] = r0.z; eaA[mt][1] = r0.w;
        eaA[mt][2] = r1.x; eaA[mt][3] = r1.y; eaA[mt][4] = r1.z; eaA[mt][5] = r1.w;
        eaA[mt][6] = r2.x; eaA[mt][7] = r2.y;
        dL[mt] = dstS[e];
    }
    float bR1[4], bR2[4];
#pragma unroll
    for (int nt = 0; nt < 4; ++nt) {
        bR1[nt] = bm1_l[nt * 16 + c16];
        bR2[nt] = bm2_l[nt * 16 + c16];
    }
    int lofs = (c16 * 4 + q) * 8;
    f32x4 zero4 = {0.f, 0.f, 0.f, 0.f};

    bf16x4 xD[2][5], xS[2][5];
#pragma unroll
    for (int mt = 0; mt < 2; ++mt) {
        const __hip_bfloat16* bd = hb + (size_t)dL[mt] * HS + q * 24;
        const __hip_bfloat16* bs = hb + (size_t)sL[mt] * HS + q * 24;
#pragma unroll
        for (int t = 0; t < 5; ++t) {
            xD[mt][t] = *(const bf16x4*)(bd + t * 4);
            xS[mt][t] = *(const bf16x4*)(bs + t * 4);
        }
    }

    // stage chunk 0 (W1 kk 0..3): 16KB, 4 rounds x 16B/thread
    {
#pragma unroll
        for (int r = 0; r < 4; ++r) {
            float4 v = ((const float4*)W1hi)[r * 256 + tid];
            ((float4*)wbuf[0])[r * 256 + tid] = v;
        }
    }

    f32x4 acc1[2][4], acc2[2][4];
#pragma unroll
    for (int mt = 0; mt < 2; ++mt)
#pragma unroll
        for (int nt = 0; nt < 4; ++nt) { acc1[mt][nt] = zero4; acc2[mt][nt] = zero4; }
    bf16x4 mR[2][4];

    // 13 chunks: c 0..8 = W1 (8x4kk + 1x3kk), c 9..12 = W2 (4x4kk)
#pragma unroll
    for (int c = 0; c < 13; ++c) {
        __syncthreads();                            // buf[c&1] ready for all waves
        // issue next-chunk global loads early (latency hides under consume below)
        float4 lv[4];
        if (c + 1 < 13) {
            const __hip_bfloat16* nsrc = (c + 1 < 9) ? (W1hi + (c + 1) * 8192)
                                                     : (W2hi + (c + 1 - 9) * 8192);
            const int nk = (c + 1 == 8) ? 3 : 4;
#pragma unroll
            for (int r = 0; r < 4; ++r)
                if (r < nk) lv[r] = ((const float4*)nsrc)[r * 256 + tid];
        }
        // consume chunk c from wbuf[c&1]
        const __hip_bfloat16* wb = wbuf[c & 1];
        if (c < 9) {
            const int nkk = (c == 8) ? 3 : 4;
#pragma unroll
            for (int kkl = 0; kkl < 4; ++kkl) {
                if (kkl < nkk) {
                    const int u = c * 4 + kkl;      // 0..34
                    bf16x8 bh[4];
#pragma unroll
                    for (int nt = 0; nt < 4; ++nt)
                        bh[nt] = *(const bf16x8*)&wb[(kkl * 4 + nt) * 512 + lofs];
#pragma unroll
                    for (int mt = 0; mt < 2; ++mt) {
                        float xv;
                        if (u < 17)      xv = bf2f(xD[mt][u >> 2][u & 3]);
                        else if (u < 34) { const int s = u - 17; xv = bf2f(xS[mt][s >> 2][s & 3]); }
                        else             xv = (q == 0) ? amfA[mt] : 0.f;
                        union { bf16x8 v; __hip_bfloat16 hx[8]; } au;
#pragma unroll
                        for (int j = 0; j < 8; ++j) au.hx[j] = __float2bfloat16(xv * eaA[mt][j]);
#pragma unroll
                        for (int nt = 0; nt < 4; ++nt)
                            acc1[mt][nt] = __builtin_amdgcn_mfma_f32_16x16x32_bf16(au.v, bh[nt], acc1[mt][nt], 0, 0, 0);
                    }
                }
            }
        } else {
#pragma unroll
            for (int kkl = 0; kkl < 4; ++kkl) {
                const int kk = (c - 9) * 4 + kkl;   // 0..15
                bf16x8 bh[4];
#pragma unroll
                for (int nt = 0; nt < 4; ++nt)
                    bh[nt] = *(const bf16x8*)&wb[(kkl * 4 + nt) * 512 + lofs];
#pragma unroll
                for (int mt = 0; mt < 2; ++mt) {
                    float mv = bf2f(mR[mt][kk >> 2][kk & 3]);
                    union { bf16x8 v; __hip_bfloat16 hx[8]; } au;
#pragma unroll
                    for (int j = 0; j < 8; ++j) au.hx[j] = __float2bfloat16(mv * eaA[mt][j]);
#pragma unroll
                    for (int nt = 0; nt < 4; ++nt)
                        acc2[mt][nt] = __builtin_amdgcn_mfma_f32_16x16x32_bf16(au.v, bh[nt], acc2[mt][nt], 0, 0, 0);
                }
            }
        }
        if (c == 8) {
            // phase-1 epilogue: stage m (wave-local rows), read transposed fragments
#pragma unroll
            for (int mt = 0; mt < 2; ++mt)
#pragma unroll
                for (int nt = 0; nt < 4; ++nt) {
                    int kd = nt * 16 + c16;
                    float bias = bR1[nt];
#pragma unroll
                    for (int r = 0; r < 4; ++r) {
                        int el = mt * 16 + q * 4 + r;
                        m_s[el * MS + kd] = __float2bfloat16(silu_f(bias + acc1[mt][nt][r]));
                    }
                }
#pragma unroll
            for (int mt = 0; mt < 2; ++mt)
#pragma unroll
                for (int t = 0; t < 4; ++t)
                    mR[mt][t] = *(const bf16x4*)&m_s[(mt * 16 + c16) * MS + q * 16 + t * 4];
            // m2 (float) writes later alias m_s (bf16) bytes — forbid TBAA reordering
            asm volatile("" ::: "memory");
        }
        // write staged regs into the other buffer (consumed after next barrier)
        if (c + 1 < 13) {
            const int nk = (c + 1 == 8) ? 3 : 4;
            float4* wdst = (float4*)wbuf[(c + 1) & 1];
#pragma unroll
            for (int r = 0; r < 4; ++r)
                if (r < nk) wdst[r * 256 + tid] = lv[r];
        }
    }

    // chunked epilogue: per mt-chunk write 16 rows of m2 (own region), run-length reduce, atomics.
    // runs spanning chunk boundaries just produce one extra atomic — still exact.
#pragma unroll
    for (int mt = 0; mt < 2; ++mt) {
#pragma unroll
        for (int nt = 0; nt < 4; ++nt) {
            int kd = nt * 16 + c16;
            float bias = bR2[nt];
#pragma unroll
            for (int r = 0; r < 4; ++r)
                m2[(q * 4 + r) * 66 + kd] = silu_f(bias + acc2[mt][nt][r]);
        }
        int rb = w * 32 + mt * 16;
        float run = 0.f;
        int cur_d = dst_s[rb];
        for (int i = 0; i < 16; ++i) {
            int d = dst_s[rb + i];                 // wave-uniform
            if (d != cur_d) {
                atomicAdd(&agg[(size_t)cur_d * 64 + l], run);
                run = 0.f;
                cur_d = d;
            }
            run += m2[i * 66 + l];
        }
        atomicAdd(&agg[(size_t)cur_d * 64 + l], run);
        asm volatile("" ::: "memory");             // chunk reads complete before next chunk overwrite
    }
}

// ---------------- K4: node update + write h/hb + agg zero ----------------
__global__ __launch_bounds__(256) void k_upd_hb(
        const float* __restrict__ h_in, const float* __restrict__ anf,
        const float* __restrict__ na, const float* __restrict__ agg_in,
        const __hip_bfloat16* __restrict__ W1hi, const __hip_bfloat16* __restrict__ W1lo,
        const float* __restrict__ bu1_l,
        const __hip_bfloat16* __restrict__ W2hi_, const __hip_bfloat16* __restrict__ W2lo_,
        const float* __restrict__ bu2_l,
        float* __restrict__ h, __hip_bfloat16* __restrict__ hb, float* __restrict__ agg) {
    __shared__ __align__(16) __hip_bfloat16 xa_s[16 * 136];
    __shared__ __align__(16) __hip_bfloat16 u1_s[16 * 72];
    __shared__ float part_s[4][16][64];
    int tid = threadIdx.x;
    int w = tid >> 6, l = tid & 63;
    int n0 = blockIdx.x * 16;
    for (int idx = tid; idx < 16 * 132; idx += 256) {
        int r = idx / 132, c = idx % 132;
        int n = n0 + r;
        float v;
        if (c < 64) v = h_in[(size_t)n * 64 + c];
        else if (c == 64) v = anf[n];
        else if (c < 129) v = agg_in[(size_t)n * 64 + (c - 65)];
        else v = 0.f;
        xa_s[r * 136 + c] = __float2bfloat16(v);
    }
    int c16 = l & 15, q = l >> 4;
    float naA[8];
#pragma unroll
    for (int j = 0; j < 8; ++j) naA[j] = na[(size_t)(n0 + c16) * 8 + j];
    __syncthreads();
    float4 z4 = {0.f, 0.f, 0.f, 0.f};
    ((float4*)(agg + (size_t)blockIdx.x * 1024))[tid] = z4;
    for (int t = tid; t < 192; t += 256)
        ((float4*)(hb + (size_t)n0 * HS))[t] = z4;
    int lofs = (c16 * 4 + q) * 8;
    zgemm_stage(xa_s, 136, 33, 33, w, c16, q, lofs, naA, W1hi, W1lo, part_s);
    __syncthreads();
    for (int t = tid; t < 1024; t += 256) {
        int row = t >> 6, col = t & 63;
        float v = part_s[0][row][col] + part_s[1][row][col] + part_s[2][row][col] +
                  part_s[3][row][col] + bu1_l[col];
        u1_s[row * 72 + col] = __float2bfloat16(silu_f(v));
    }
    __syncthreads();
    zgemm_stage(u1_s, 72, 16, 16, w, c16, q, lofs, naA, W2hi_, W2lo_, part_s);
    __syncthreads();
    for (int t = tid; t < 1024; t += 256) {
        int row = t >> 6, col = t & 63;
        float v = part_s[0][row][col] + part_s[1][row][col] + part_s[2][row][col] +
                  part_s[3][row][col] + bu2_l[col];
        int n = n0 + row;
        float hn = h[(size_t)n * 64 + col] + v;
        h[(size_t)n * 64 + col] = hn;
        hb[(size_t)n * HS + (col / 17) * 24 + col % 17] = __float2bfloat16(hn);
    }
    if (tid < 16) hb[(size_t)(n0 + tid) * HS + 85] = __float2bfloat16(anf[n0 + tid]);
}

// ---------------- K6: fused node update (layer 1) + prepool -> p2 ----------------
__global__ __launch_bounds__(256) void k_upd_prepool(
        const float* __restrict__ h_in, const float* __restrict__ anf,
        const float* __restrict__ na, const float* __restrict__ agg_in,
        const __hip_bfloat16* __restrict__ W1hi, const __hip_bfloat16* __restrict__ W1lo,
        const float* __restrict__ bu1_l,
        const __hip_bfloat16* __restrict__ W2hi_, const __hip_bfloat16* __restrict__ W2lo_,
        const float* __restrict__ bu2_l,
        const __hip_bfloat16* __restrict__ Wp1hi, const __hip_bfloat16* __restrict__ Wp1lo,
        const float* __restrict__ bp1,
        const __hip_bfloat16* __restrict__ Wp2hi, const __hip_bfloat16* __restrict__ Wp2lo,
        const float* __restrict__ bp2,
        float* __restrict__ p2) {
    __shared__ __align__(16) __hip_bfloat16 xa_s[16 * 136];
    __shared__ __align__(16) __hip_bfloat16 u1_s[16 * 72];
    __shared__ __align__(16) __hip_bfloat16 x2_s[16 * 72];
    __shared__ float part_s[4][16][64];
    int tid = threadIdx.x;
    int w = tid >> 6, l = tid & 63;
    int n0 = blockIdx.x * 16;
    for (int idx = tid; idx < 16 * 132; idx += 256) {
        int r = idx / 132, c = idx % 132;
        int n = n0 + r;
        float v;
        if (c < 64) v = h_in[(size_t)n * 64 + c];
        else if (c == 64) v = anf[n];
        else if (c < 129) v = agg_in[(size_t)n * 64 + (c - 65)];
        else v = 0.f;
        xa_s[r * 136 + c] = __float2bfloat16(v);
    }
    int c16 = l & 15, q = l >> 4;
    float naA[8];
#pragma unroll
    for (int j = 0; j < 8; ++j) naA[j] = na[(size_t)(n0 + c16) * 8 + j];
    __syncthreads();
    int lofs = (c16 * 4 + q) * 8;
    zgemm_stage(xa_s, 136, 33, 33, w, c16, q, lofs, naA, W1hi, W1lo, part_s);
    __syncthreads();
    for (int t = tid; t < 1024; t += 256) {
        int row = t >> 6, col = t & 63;
        float v = part_s[0][row][col] + part_s[1][row][col] + part_s[2][row][col] +
                  part_s[3][row][col] + bu1_l[col];
        u1_s[row * 72 + col] = __float2bfloat16(silu_f(v));
    }
    __syncthreads();
    zgemm_stage(u1_s, 72, 16, 16, w, c16, q, lofs, naA, W2hi_, W2lo_, part_s);
    __syncthreads();
    for (int t = tid; t < 1024; t += 256) {
        int row = t >> 6, col = t & 63;
        float v = part_s[0][row][col] + part_s[1][row][col] + part_s[2][row][col] +
                  part_s[3][row][col] + bu2_l[col];
        float hn = h_in[(size_t)(n0 + row) * 64 + col] + v;
        x2_s[row * 72 + col] = __float2bfloat16(hn);
    }
    __syncthreads();
    zgemm_stage(x2_s, 72, 16, 16, w, c16, q, lofs, naA, Wp1hi, Wp1lo, part_s);
    __syncthreads();
    for (int t = tid; t < 1024; t += 256) {
        int row = t >> 6, col = t & 63;
        float v = part_s[0][row][col] + part_s[1][row][col] + part_s[2][row][col] +
                  part_s[3][row][col] + bp1[col];
        u1_s[row * 72 + col] = __float2bfloat16(silu_f(v));
    }
    __syncthreads();
    zgemm_stage(u1_s, 72, 16, 16, w, c16, q, lofs, naA, Wp2hi, Wp2lo, part_s);
    __syncthreads();
    for (int t = tid; t < 1024; t += 256) {
        int row = t >> 6, col = t & 63;
        float v = part_s[0][row][col] + part_s[1][row][col] + part_s[2][row][col] +
                  part_s[3][row][col] + bp2[col];
        p2[(size_t)(n0 + row) * 64 + col] = v;
    }
}

// ---------------- K_pool ----------------
__global__ __launch_bounds__(256) void k_pool(
        const float* __restrict__ p2, const int* __restrict__ batch,
        float* __restrict__ partial_p, float* __restrict__ partial_cnt) {
    __shared__ float acc_s[16 * 64];
    __shared__ float cnt_s[16];
    int tid = threadIdx.x;
    for (int idx = tid; idx < 1024; idx += 256) acc_s[idx] = 0.f;
    if (tid < 16) cnt_s[tid] = 0.f;
    __syncthreads();
    int w = tid >> 6, k = tid & 63;
    int base = blockIdx.x * 125;
    for (int i = 0; i < 32; ++i) {
        int nl = i * 4 + w;
        if (nl < 125) {
            int n = base + nl;
            int b = batch[n];
            atomicAdd(&acc_s[b * 64 + k], p2[(size_t)n * 64 + k]);
            if (k == 0) atomicAdd(&cnt_s[b], 1.0f);
        }
    }
    __syncthreads();
    for (int idx = tid; idx < 1024; idx += 256)
        partial_p[(size_t)blockIdx.x * 1024 + idx] = acc_s[idx];
    if (tid < 16) partial_cnt[blockIdx.x * 16 + tid] = cnt_s[tid];
}

// ---------------- K7: reduce partials, mean, final MLP ----------------
__global__ __launch_bounds__(1024) void k_final(
        const float* __restrict__ partial_p, const float* __restrict__ partial_cnt,
        const float* __restrict__ Wq1, const float* __restrict__ bq1,
        const float* __restrict__ Wq2, const float* __restrict__ bq2,
        float* __restrict__ out) {
    __shared__ float g[16][64];
    int b = threadIdx.x >> 6, k = threadIdx.x & 63;
    float s = 0.f, cc = 0.f;
    for (int c = 0; c < POOL_CHUNKS; ++c) s += partial_p[(size_t)c * 1024 + b * 64 + k];
    for (int c = 0; c < POOL_CHUNKS; ++c) cc += partial_cnt[c * 16 + b];
    g[b][k] = s / fmaxf(cc, 1.0f);
    __syncthreads();
    float acc = bq1[k];
#pragma unroll
    for (int i = 0; i < 64; ++i) acc = fmaf(g[b][i], Wq1[i * 64 + k], acc);
    float v = silu_f(acc) * Wq2[k];
#pragma unroll
    for (int off = 32; off > 0; off >>= 1) v += __shfl_down(v, off, 64);
    if (k == 0) out[b] = v + bq2[0];
}

extern "C" void kernel_launch(void* const* d_in, const int* in_sizes, int n_in,
                              void* d_out, int out_size, void* d_ws, size_t ws_size,
                              hipStream_t stream) {
    const float* x    = (const float*)d_in[0];
    const int*   eidx = (const int*)  d_in[1];
    const float* ea   = (const float*)d_in[2];
    const float* na   = (const float*)d_in[3];
    const float* amf  = (const float*)d_in[4];
    const float* anf  = (const float*)d_in[5];
    const int*   batch= (const int*)  d_in[6];
    const float* W_emb= (const float*)d_in[7];
    const float* b_emb= (const float*)d_in[8];
    const float* Wm1  = (const float*)d_in[9];
    const float* bm1  = (const float*)d_in[10];
    const float* Wm2  = (const float*)d_in[11];
    const float* bm2  = (const float*)d_in[12];
    const float* Wu1  = (const float*)d_in[13];
    const float* bu1  = (const float*)d_in[14];
    const float* Wu2  = (const float*)d_in[15];
    const float* bu2  = (const float*)d_in[16];
    const float* Wp1  = (const float*)d_in[17];
    const float* bp1  = (const float*)d_in[18];
    const float* Wp2  = (const float*)d_in[19];
    const float* bp2  = (const float*)d_in[20];
    const float* Wq1  = (const float*)d_in[21];
    const float* bq1  = (const float*)d_in[22];
    const float* Wq2  = (const float*)d_in[23];
    const float* bq2  = (const float*)d_in[24];

    float* ws = (float*)d_ws;
    float* h      = ws;                            // N*64
    float* agg    = h + (size_t)N * 64;            // N*64
    float* p2     = agg + (size_t)N * 64;          // N*64
    float* part_p = p2 + (size_t)N * 64;           // 80*1024
    float* part_c = part_p + POOL_CHUNKS * 1024;   // 80*16
    float* fend   = part_c + POOL_CHUNKS * 16;
    __hip_bfloat16* hb     = (__hip_bfloat16*)fend;          // N*96
    __hip_bfloat16* W2hi   = hb + (size_t)N * HS;            // 2*32768
    __hip_bfloat16* Wm1zhi = W2hi + 65536;                   // 2*71680
    __hip_bfloat16* Wu1hi  = Wm1zhi + 143360;                // 2*67584
    __hip_bfloat16* Wu1lo  = Wu1hi + 135168;
    __hip_bfloat16* Wu2hi  = Wu1lo + 135168;                 // 2*32768
    __hip_bfloat16* Wu2lo  = Wu2hi + 65536;
    __hip_bfloat16* Wp1hi  = Wu2lo + 65536;                  // 32768
    __hip_bfloat16* Wp1lo  = Wp1hi + 32768;
    __hip_bfloat16* Wp2hi  = Wp1lo + 32768;
    __hip_bfloat16* Wp2lo  = Wp2hi + 32768;
    int* hist   = (int*)(Wp2lo + 32768);                     // N
    int* cursor = hist + N;                                  // N
    int* dstS   = cursor + N;                                // E
    float4* recs = (float4*)(dstS + E);                      // E * 3 float4 (48B/edge)

    // mega pre-kernel: all weight reorders + hist zero + embed(+agg/hb init)
    k_pre<<<PB_TOTAL, 256, 0, stream>>>(
        Wm2, W2hi, Wm1, Wm1zhi, Wu1, Wu1hi, Wu1lo, Wu2, Wu2hi, Wu2lo,
        Wp1, Wp1hi, Wp1lo, Wp2, Wp2hi, Wp2lo, hist,
        x, anf, na, W_emb, b_emb, h, hb, agg);

    // dst-sort + materialize sorted edge records (reused by both edge dispatches)
    k_hist<<<(E + 255) / 256, 256, 0, stream>>>(eidx, hist);
    k_scan<<<1, 1024, 0, stream>>>(hist, cursor);
    k_scatter_sort<<<(E + 255) / 256, 256, 0, stream>>>(eidx, ea, amf, cursor, dstS, recs);

    k_edge<<<E / 128, 256, 0, stream>>>(recs, dstS, hb,
                                        Wm1zhi, bm1, W2hi, bm2, agg);
    k_upd_hb<<<625, 256, 0, stream>>>(h, anf, na, agg,
                                      Wu1hi, Wu1lo, bu1,
                                      Wu2hi, Wu2lo, bu2,
                                      h, hb, agg);
    k_edge<<<E / 128, 256, 0, stream>>>(recs, dstS, hb,
                                        Wm1zhi + 71680, bm1 + 64,
                                        W2hi + 32768, bm2 + 64, agg);
    k_upd_prepool<<<625, 256, 0, stream>>>(h, anf, na, agg,
                                           Wu1hi + 67584, Wu1lo + 67584, bu1 + 64,
                                           Wu2hi + 32768, Wu2lo + 32768, bu2 + 64,
                                           Wp1hi, Wp1lo, bp1, Wp2hi, Wp2lo, bp2, p2);
    k_pool<<<POOL_CHUNKS, 256, 0, stream>>>(p2, batch, part_p, part_c);
    k_final<<<1, 1024, 0, stream>>>(part_p, part_c, Wq1, bq1, Wq2, bq2, (float*)d_out);
}

// Round 8
// 370.987 us; speedup vs baseline: 1.0474x; 1.0061x over previous
//
#include <hip/hip_runtime.h>
#include <hip/hip_bf16.h>
#include <math.h>

// Problem constants
constexpr int N = 10000;
constexpr int E = 160000;
constexpr int B = 16;
constexpr int POOL_CHUNKS = 80;   // 80 * 125 = 10000
constexpr int MS = 72;            // m_s row stride (bf16), wave-local
constexpr int HS = 96;            // hb row stride: 4 q-sections x 24 (17 used + pad)

typedef short bf16x8 __attribute__((ext_vector_type(8)));
typedef short bf16x4 __attribute__((ext_vector_type(4)));
typedef float f32x4 __attribute__((ext_vector_type(4)));

__device__ __forceinline__ float silu_f(float x) {
    return x / (1.0f + __expf(-x));
}
__device__ __forceinline__ float bf2f(short s) {
    union { unsigned u; float f; } c; c.u = (unsigned)(unsigned short)s << 16; return c.f;
}

// ---------------- weight reorder bodies (q-major i-mapping) ----------------
__device__ __forceinline__ void w2_body(
        int idx, const float* __restrict__ Wsrc,
        __hip_bfloat16* __restrict__ Whi, __hip_bfloat16* __restrict__ Wlo) {
    int l = idx >> 15;
    int rem = idx & 32767;
    int kk = rem >> 11;
    int nt = (rem >> 9) & 3;
    int c  = (rem >> 5) & 15;
    int q  = (rem >> 3) & 3;
    int j  = rem & 7;
    int i = q * 16 + kk;
    int k = nt * 16 + c;
    float wv = Wsrc[(size_t)l * 32768 + i * 512 + j * 64 + k];
    __hip_bfloat16 hi = __float2bfloat16(wv);
    Whi[idx] = hi;
    Wlo[idx] = __float2bfloat16(wv - __bfloat162float(hi));
}

__device__ __forceinline__ void w2h_body(
        int idx, const float* __restrict__ Wsrc, __hip_bfloat16* __restrict__ Whi) {
    int l = idx >> 15;
    int rem = idx & 32767;
    int kk = rem >> 11;
    int nt = (rem >> 9) & 3;
    int c  = (rem >> 5) & 15;
    int q  = (rem >> 3) & 3;
    int j  = rem & 7;
    int i = q * 16 + kk;
    int k = nt * 16 + c;
    Whi[idx] = __float2bfloat16(Wsrc[(size_t)l * 32768 + i * 512 + j * 64 + k]);
}

__device__ __forceinline__ void wu1_body(
        int idx, const float* __restrict__ Wu1,
        __hip_bfloat16* __restrict__ Whi, __hip_bfloat16* __restrict__ Wlo) {
    int l = idx / 67584;
    int rem = idx % 67584;
    int kk = rem / 2048;          // 0..32
    int r2 = rem % 2048;
    int nt = (r2 >> 9) & 3;
    int c  = (r2 >> 5) & 15;
    int q  = (r2 >> 3) & 3;
    int j  = r2 & 7;
    int i = q * 33 + kk;          // 0..131
    float wv = (i < 129) ? Wu1[(size_t)l * 129 * 512 + i * 512 + j * 64 + nt * 16 + c] : 0.f;
    __hip_bfloat16 hi = __float2bfloat16(wv);
    Whi[idx] = hi;
    Wlo[idx] = __float2bfloat16(wv - __bfloat162float(hi));
}

__device__ __forceinline__ void wm1z_body(
        int idx, const float* __restrict__ Wm1, __hip_bfloat16* __restrict__ Whi) {
    int l = idx / 71680;
    int rem = idx % 71680;
    int kkn = rem >> 9;          // 0..139
    int off = rem & 511;
    int kk = kkn >> 2;
    int nt = kkn & 3;
    int c16 = off >> 5;
    int q = (off >> 3) & 3;
    int j = off & 7;
    int k = nt * 16 + c16;
    int wi = -1;
    if (kk < 17) { int i = q * 17 + kk; if (i <= 64) wi = i; }
    else if (kk < 34) { int s = q * 17 + (kk - 17); if (s <= 64) wi = 65 + s; }
    else { if (q == 0) wi = 130; }
    float wv = (wi >= 0) ? Wm1[((size_t)l * 131 + wi) * 512 + j * 64 + k] : 0.f;
    Whi[idx] = __float2bfloat16(wv);
}

// ---------------- mega pre-kernel: all weight reorders + hist zero + embed ----------------
constexpr int PB_W2H  = 0;                 // 256 blocks: Wm2 -> W2hi
constexpr int PB_WM1Z = PB_W2H  + 256;     // 560
constexpr int PB_WU1  = PB_WM1Z + 560;     // 528
constexpr int PB_WU2  = PB_WU1  + 528;     // 256
constexpr int PB_WP1  = PB_WU2  + 256;     // 128
constexpr int PB_WP2  = PB_WP1  + 128;     // 128
constexpr int PB_ZERO = PB_WP2  + 128;     // 40
constexpr int PB_EMB  = PB_ZERO + 40;      // 625
constexpr int PB_TOTAL= PB_EMB  + 625;     // 2521

__global__ __launch_bounds__(256) void k_pre(
        const float* __restrict__ Wm2, __hip_bfloat16* __restrict__ W2hi,
        const float* __restrict__ Wm1, __hip_bfloat16* __restrict__ Wm1zhi,
        const float* __restrict__ Wu1w, __hip_bfloat16* __restrict__ Wu1hi, __hip_bfloat16* __restrict__ Wu1lo,
        const float* __restrict__ Wu2w, __hip_bfloat16* __restrict__ Wu2hi, __hip_bfloat16* __restrict__ Wu2lo,
        const float* __restrict__ Wp1w, __hip_bfloat16* __restrict__ Wp1hi, __hip_bfloat16* __restrict__ Wp1lo,
        const float* __restrict__ Wp2w, __hip_bfloat16* __restrict__ Wp2hi, __hip_bfloat16* __restrict__ Wp2lo,
        int* __restrict__ hist,
        const float* __restrict__ x, const float* __restrict__ anf,
        const float* __restrict__ na, const float* __restrict__ W_emb,
        const float* __restrict__ b_emb,
        float* __restrict__ h, __hip_bfloat16* __restrict__ hb, float* __restrict__ agg) {
    __shared__ float xs[16][18];
    __shared__ float na_s[16][8];
    int tid = threadIdx.x;
    int bx = blockIdx.x;
    if (bx < PB_WM1Z) {
        w2h_body((bx - PB_W2H) * 256 + tid, Wm2, W2hi);
    } else if (bx < PB_WU1) {
        wm1z_body((bx - PB_WM1Z) * 256 + tid, Wm1, Wm1zhi);
    } else if (bx < PB_WU2) {
        wu1_body((bx - PB_WU1) * 256 + tid, Wu1w, Wu1hi, Wu1lo);
    } else if (bx < PB_WP1) {
        w2_body((bx - PB_WU2) * 256 + tid, Wu2w, Wu2hi, Wu2lo);
    } else if (bx < PB_WP2) {
        w2_body((bx - PB_WP1) * 256 + tid, Wp1w, Wp1hi, Wp1lo);
    } else if (bx < PB_ZERO) {
        w2_body((bx - PB_WP2) * 256 + tid, Wp2w, Wp2hi, Wp2lo);
    } else if (bx < PB_EMB) {
        int i = (bx - PB_ZERO) * 256 + tid;
        if (i < N) hist[i] = 0;
    } else {
        // ---- embed: h fp32 + hb (q-sectioned) + agg zero ----
        int eb = bx - PB_EMB;
        int w = tid >> 6, l = tid & 63;
        int n0 = eb * 16;
        {
            int r = tid >> 4, c = tid & 15;
            xs[r][c] = x[(size_t)(n0 + r) * 16 + c];
        }
        if (tid < 16) xs[tid][16] = anf[n0 + tid];
        if (tid < 128) na_s[tid >> 3][tid & 7] = na[(size_t)n0 * 8 + tid];
        float4 z4 = {0.f, 0.f, 0.f, 0.f};
        ((float4*)(agg + (size_t)eb * 1024))[tid] = z4;
        for (int t = tid; t < 192; t += 256)
            ((float4*)(hb + (size_t)n0 * HS))[t] = z4;
        __syncthreads();
        float acc[4];
#pragma unroll
        for (int t = 0; t < 4; ++t) acc[t] = b_emb[l];
        for (int i = 0; i < 17; ++i) {
#pragma unroll
            for (int j = 0; j < 8; ++j) {
                float wv = W_emb[(i * 8 + j) * 64 + l];
#pragma unroll
                for (int t = 0; t < 4; ++t) {
                    int nn = w * 4 + t;
                    acc[t] = fmaf(xs[nn][i] * na_s[nn][j], wv, acc[t]);
                }
            }
        }
        int slot = (l / 17) * 24 + l % 17;
#pragma unroll
        for (int t = 0; t < 4; ++t) {
            int n = n0 + w * 4 + t;
            h[(size_t)n * 64 + l] = acc[t];
            hb[(size_t)n * HS + slot] = __float2bfloat16(acc[t]);
        }
        if (tid < 16) hb[(size_t)(n0 + tid) * HS + 85] = __float2bfloat16(xs[tid][16]);
    }
}

// ---------------- edge sort by dst: histogram / scan / scatter+materialize ----------------
__global__ __launch_bounds__(256) void k_hist(
        const int* __restrict__ eidx, int* __restrict__ hist) {
    int e = blockIdx.x * 256 + threadIdx.x;
    if (e < E) atomicAdd(&hist[eidx[E + e]], 1);
}

// single-block exclusive scan over N=10000 bins -> cursor
__global__ __launch_bounds__(1024) void k_scan(
        const int* __restrict__ hist, int* __restrict__ cursor) {
    __shared__ int wsum[16];
    int t = threadIdx.x;
    int base = t * 10;
    int loc[10];
    int s = 0;
#pragma unroll
    for (int i = 0; i < 10; ++i) {
        int v = (base + i < N) ? hist[base + i] : 0;
        loc[i] = s;
        s += v;
    }
    int lane = t & 63, w = t >> 6;
    int incl = s;
    for (int off = 1; off < 64; off <<= 1) {
        int u = __shfl_up(incl, off, 64);
        if (lane >= off) incl += u;
    }
    if (lane == 63) wsum[w] = incl;
    __syncthreads();
    if (t == 0) {
        int a = 0;
        for (int i2 = 0; i2 < 16; ++i2) { int v = wsum[i2]; wsum[i2] = a; a += v; }
    }
    __syncthreads();
    int excl = incl - s + wsum[w];
#pragma unroll
    for (int i = 0; i < 10; ++i) {
        int p = base + i;
        if (p < N) cursor[p] = excl + loc[i];
    }
}

// scatter into dst-sorted records (coalesced reads; 48B record = 1-2 line touches/edge)
__global__ __launch_bounds__(256) void k_scatter_sort(
        const int* __restrict__ eidx, const float* __restrict__ ea,
        const float* __restrict__ amf, int* __restrict__ cursor,
        int* __restrict__ dstS, float4* __restrict__ recs) {
    int e = blockIdx.x * 256 + threadIdx.x;
    if (e < E) {
        int d = eidx[E + e];
        int p = atomicAdd(&cursor[d], 1);
        dstS[p] = d;
        float4 a0 = ((const float4*)ea)[(size_t)e * 2];
        float4 a1 = ((const float4*)ea)[(size_t)e * 2 + 1];
        float4 r0 = {__int_as_float(eidx[e]), amf[e], a0.x, a0.y};
        float4 r1 = {a0.z, a0.w, a1.x, a1.y};
        float4 r2 = {a1.z, a1.w, 0.f, 0.f};
        recs[(size_t)p * 3 + 0] = r0;
        recs[(size_t)p * 3 + 1] = r1;
        recs[(size_t)p * 3 + 2] = r2;
    }
}

// ---------------- device helper: one z-GEMM stage (hi/lo), 4 waves split K, q-major x ----------------
__device__ __forceinline__ void zgemm_stage(
        const __hip_bfloat16* xsrc, int xstride, int kkmax, int Lq,
        int w, int c16, int q, int lofs, const float* naA,
        const __hip_bfloat16* __restrict__ Whi, const __hip_bfloat16* __restrict__ Wlo,
        float (*part_s)[16][64]) {
    f32x4 zero4 = {0.f, 0.f, 0.f, 0.f};
    f32x4 acc[4];
#pragma unroll
    for (int nt = 0; nt < 4; ++nt) acc[nt] = zero4;
    for (int kk = w; kk < kkmax; kk += 4) {
        bf16x8 bh[4], bl[4];
#pragma unroll
        for (int nt = 0; nt < 4; ++nt) {
            int off = (kk * 4 + nt) * 512 + lofs;
            bh[nt] = *(const bf16x8*)(Whi + off);
            bl[nt] = *(const bf16x8*)(Wlo + off);
        }
        float mv = __bfloat162float(xsrc[c16 * xstride + q * Lq + kk]);
        union { bf16x8 v; __hip_bfloat16 hx[8]; } au;
#pragma unroll
        for (int j = 0; j < 8; ++j) au.hx[j] = __float2bfloat16(mv * naA[j]);
#pragma unroll
        for (int nt = 0; nt < 4; ++nt) {
            acc[nt] = __builtin_amdgcn_mfma_f32_16x16x32_bf16(au.v, bh[nt], acc[nt], 0, 0, 0);
            acc[nt] = __builtin_amdgcn_mfma_f32_16x16x32_bf16(au.v, bl[nt], acc[nt], 0, 0, 0);
        }
    }
#pragma unroll
    for (int nt = 0; nt < 4; ++nt)
#pragma unroll
        for (int r = 0; r < 4; ++r) part_s[w][q * 4 + r][nt * 16 + c16] = acc[nt][r];
}

// ---------------- K3: edge kernel — LDS-staged weights (dbuf), slim register footprint ----------------
// r7's unified staged loop worked but spilled (~17 regs: WRITE 4.8->26MB, FETCH 12->18.6MB).
// Two pressure cuts, no schedule change:
//  (1) ONE accumulator reused across phases: acc is fully drained into m_s/mR at the c==8
//      epilogue, then re-zeroed for phase 2. -32 concurrent regs.
//  (2) xS gather deferred to c==3 (first use chunk 4): xD dies at chunk 4, so the 40-reg
//      xD+xS overlap shrinks to a 1-chunk window; 1-chunk prefetch covers L2-resident hb.
__global__ __launch_bounds__(256, 3) void k_edge(
        const float4* __restrict__ recs, const int* __restrict__ dstS,
        const __hip_bfloat16* __restrict__ hb,
        const __hip_bfloat16* __restrict__ W1hi, const float* __restrict__ bm1_l,
        const __hip_bfloat16* __restrict__ W2hi,
        const float* __restrict__ bm2_l, float* __restrict__ agg) {
    __shared__ __align__(16) __hip_bfloat16 wbuf[2][8192];   // 2 x 16KB weight chunks
    // per-wave private 4608B region: m_s [32][72] bf16; m2 chunk [16][66] f32 overlaid
    __shared__ __align__(16) char smem_u[4 * 4608];          // 18432 B
    __shared__ int dst_s[128];
    int tid = threadIdx.x;
    int l = tid & 63, w = tid >> 6;
    int e0 = blockIdx.x * 128;
    __hip_bfloat16* m_s = (__hip_bfloat16*)(smem_u + w * 4608);
    float* m2 = (float*)(smem_u + w * 4608);

    if (l < 32) dst_s[w * 32 + l] = dstS[e0 + w * 32 + l];

    int c16 = l & 15, q = l >> 4;
    int e0w = w * 32;
    float eaA[2][8], amfA[2];
    int dL[2], sL[2];
#pragma unroll
    for (int mt = 0; mt < 2; ++mt) {
        int e = e0 + e0w + mt * 16 + c16;
        float4 r0 = recs[(size_t)e * 3];
        float4 r1 = recs[(size_t)e * 3 + 1];
        float4 r2 = recs[(size_t)e * 3 + 2];
        sL[mt] = __float_as_int(r0.x);
        amfA[mt] = r0.y;
        eaA[mt][0] = r0.z; eaA[mt][1] = r0.w;
        eaA[mt][2] = r1.x; eaA[mt][3] = r1.y; eaA[mt][4] = r1.z; eaA[mt][5] = r1.w;
        eaA[mt][6] = r2.x; eaA[mt][7] = r2.y;
        dL[mt] = dstS[e];
    }
    float bR1[4], bR2[4];
#pragma unroll
    for (int nt = 0; nt < 4; ++nt) {
        bR1[nt] = bm1_l[nt * 16 + c16];
        bR2[nt] = bm2_l[nt * 16 + c16];
    }
    int lofs = (c16 * 4 + q) * 8;
    f32x4 zero4 = {0.f, 0.f, 0.f, 0.f};

    // gather D-side fragments only (S-side deferred to c==3)
    bf16x4 xD[2][5];
#pragma unroll
    for (int mt = 0; mt < 2; ++mt) {
        const __hip_bfloat16* bd = hb + (size_t)dL[mt] * HS + q * 24;
#pragma unroll
        for (int t = 0; t < 5; ++t)
            xD[mt][t] = *(const bf16x4*)(bd + t * 4);
    }

    // stage chunk 0 (W1 kk 0..3): 16KB, 4 rounds x 16B/thread
    {
#pragma unroll
        for (int r = 0; r < 4; ++r) {
            float4 v = ((const float4*)W1hi)[r * 256 + tid];
            ((float4*)wbuf[0])[r * 256 + tid] = v;
        }
    }

    f32x4 acc[2][4];
#pragma unroll
    for (int mt = 0; mt < 2; ++mt)
#pragma unroll
        for (int nt = 0; nt < 4; ++nt) acc[mt][nt] = zero4;
    bf16x4 xS[2][5];    // loaded at c==3
    bf16x4 mR[2][4];    // loaded at c==8

    // 13 chunks: c 0..8 = W1 (8x4kk + 1x3kk), c 9..12 = W2 (4x4kk)
#pragma unroll
    for (int c = 0; c < 13; ++c) {
        __syncthreads();                            // buf[c&1] ready for all waves
        // issue next-chunk global loads early (latency hides under consume below)
        float4 lv[4];
        if (c + 1 < 13) {
            const __hip_bfloat16* nsrc = (c + 1 < 9) ? (W1hi + (c + 1) * 8192)
                                                     : (W2hi + (c + 1 - 9) * 8192);
            const int nk = (c + 1 == 8) ? 3 : 4;
#pragma unroll
            for (int r = 0; r < 4; ++r)
                if (r < nk) lv[r] = ((const float4*)nsrc)[r * 256 + tid];
        }
        if (c == 3) {
            // prefetch S-side gathers (first used in chunk 4); xD is nearly dead by then
#pragma unroll
            for (int mt = 0; mt < 2; ++mt) {
                const __hip_bfloat16* bs = hb + (size_t)sL[mt] * HS + q * 24;
#pragma unroll
                for (int t = 0; t < 5; ++t)
                    xS[mt][t] = *(const bf16x4*)(bs + t * 4);
            }
        }
        // consume chunk c from wbuf[c&1]
        const __hip_bfloat16* wb = wbuf[c & 1];
        if (c < 9) {
            const int nkk = (c == 8) ? 3 : 4;
#pragma unroll
            for (int kkl = 0; kkl < 4; ++kkl) {
                if (kkl < nkk) {
                    const int u = c * 4 + kkl;      // 0..34
                    bf16x8 bh[4];
#pragma unroll
                    for (int nt = 0; nt < 4; ++nt)
                        bh[nt] = *(const bf16x8*)&wb[(kkl * 4 + nt) * 512 + lofs];
#pragma unroll
                    for (int mt = 0; mt < 2; ++mt) {
                        float xv;
                        if (u < 17)      xv = bf2f(xD[mt][u >> 2][u & 3]);
                        else if (u < 34) { const int s = u - 17; xv = bf2f(xS[mt][s >> 2][s & 3]); }
                        else             xv = (q == 0) ? amfA[mt] : 0.f;
                        union { bf16x8 v; __hip_bfloat16 hx[8]; } au;
#pragma unroll
                        for (int j = 0; j < 8; ++j) au.hx[j] = __float2bfloat16(xv * eaA[mt][j]);
#pragma unroll
                        for (int nt = 0; nt < 4; ++nt)
                            acc[mt][nt] = __builtin_amdgcn_mfma_f32_16x16x32_bf16(au.v, bh[nt], acc[mt][nt], 0, 0, 0);
                    }
                }
            }
        } else {
#pragma unroll
            for (int kkl = 0; kkl < 4; ++kkl) {
                const int kk = (c - 9) * 4 + kkl;   // 0..15
                bf16x8 bh[4];
#pragma unroll
                for (int nt = 0; nt < 4; ++nt)
                    bh[nt] = *(const bf16x8*)&wb[(kkl * 4 + nt) * 512 + lofs];
#pragma unroll
                for (int mt = 0; mt < 2; ++mt) {
                    float mv = bf2f(mR[mt][kk >> 2][kk & 3]);
                    union { bf16x8 v; __hip_bfloat16 hx[8]; } au;
#pragma unroll
                    for (int j = 0; j < 8; ++j) au.hx[j] = __float2bfloat16(mv * eaA[mt][j]);
#pragma unroll
                    for (int nt = 0; nt < 4; ++nt)
                        acc[mt][nt] = __builtin_amdgcn_mfma_f32_16x16x32_bf16(au.v, bh[nt], acc[mt][nt], 0, 0, 0);
                }
            }
        }
        if (c == 8) {
            // phase-1 epilogue: drain acc -> m_s, read transposed fragments, re-zero acc
#pragma unroll
            for (int mt = 0; mt < 2; ++mt)
#pragma unroll
                for (int nt = 0; nt < 4; ++nt) {
                    int kd = nt * 16 + c16;
                    float bias = bR1[nt];
#pragma unroll
                    for (int r = 0; r < 4; ++r) {
                        int el = mt * 16 + q * 4 + r;
                        m_s[el * MS + kd] = __float2bfloat16(silu_f(bias + acc[mt][nt][r]));
                    }
                }
#pragma unroll
            for (int mt = 0; mt < 2; ++mt)
#pragma unroll
                for (int t = 0; t < 4; ++t)
                    mR[mt][t] = *(const bf16x4*)&m_s[(mt * 16 + c16) * MS + q * 16 + t * 4];
            // m2 (float) writes later alias m_s (bf16) bytes — forbid TBAA reordering
            asm volatile("" ::: "memory");
#pragma unroll
            for (int mt = 0; mt < 2; ++mt)
#pragma unroll
                for (int nt = 0; nt < 4; ++nt) acc[mt][nt] = zero4;   // reuse for phase 2
        }
        // write staged regs into the other buffer (consumed after next barrier)
        if (c + 1 < 13) {
            const int nk = (c + 1 == 8) ? 3 : 4;
            float4* wdst = (float4*)wbuf[(c + 1) & 1];
#pragma unroll
            for (int r = 0; r < 4; ++r)
                if (r < nk) wdst[r * 256 + tid] = lv[r];
        }
    }

    // chunked epilogue: per mt-chunk write 16 rows of m2 (own region), run-length reduce, atomics.
    // runs spanning chunk boundaries just produce one extra atomic — still exact.
#pragma unroll
    for (int mt = 0; mt < 2; ++mt) {
#pragma unroll
        for (int nt = 0; nt < 4; ++nt) {
            int kd = nt * 16 + c16;
            float bias = bR2[nt];
#pragma unroll
            for (int r = 0; r < 4; ++r)
                m2[(q * 4 + r) * 66 + kd] = silu_f(bias + acc[mt][nt][r]);
        }
        int rb = w * 32 + mt * 16;
        float run = 0.f;
        int cur_d = dst_s[rb];
        for (int i = 0; i < 16; ++i) {
            int d = dst_s[rb + i];                 // wave-uniform
            if (d != cur_d) {
                atomicAdd(&agg[(size_t)cur_d * 64 + l], run);
                run = 0.f;
                cur_d = d;
            }
            run += m2[i * 66 + l];
        }
        atomicAdd(&agg[(size_t)cur_d * 64 + l], run);
        asm volatile("" ::: "memory");             // chunk reads complete before next chunk overwrite
    }
}

// ---------------- K4: node update + write h/hb + agg zero ----------------
__global__ __launch_bounds__(256) void k_upd_hb(
        const float* __restrict__ h_in, const float* __restrict__ anf,
        const float* __restrict__ na, const float* __restrict__ agg_in,
        const __hip_bfloat16* __restrict__ W1hi, const __hip_bfloat16* __restrict__ W1lo,
        const float* __restrict__ bu1_l,
        const __hip_bfloat16* __restrict__ W2hi_, const __hip_bfloat16* __restrict__ W2lo_,
        const float* __restrict__ bu2_l,
        float* __restrict__ h, __hip_bfloat16* __restrict__ hb, float* __restrict__ agg) {
    __shared__ __align__(16) __hip_bfloat16 xa_s[16 * 136];
    __shared__ __align__(16) __hip_bfloat16 u1_s[16 * 72];
    __shared__ float part_s[4][16][64];
    int tid = threadIdx.x;
    int w = tid >> 6, l = tid & 63;
    int n0 = blockIdx.x * 16;
    for (int idx = tid; idx < 16 * 132; idx += 256) {
        int r = idx / 132, c = idx % 132;
        int n = n0 + r;
        float v;
        if (c < 64) v = h_in[(size_t)n * 64 + c];
        else if (c == 64) v = anf[n];
        else if (c < 129) v = agg_in[(size_t)n * 64 + (c - 65)];
        else v = 0.f;
        xa_s[r * 136 + c] = __float2bfloat16(v);
    }
    int c16 = l & 15, q = l >> 4;
    float naA[8];
#pragma unroll
    for (int j = 0; j < 8; ++j) naA[j] = na[(size_t)(n0 + c16) * 8 + j];
    __syncthreads();
    float4 z4 = {0.f, 0.f, 0.f, 0.f};
    ((float4*)(agg + (size_t)blockIdx.x * 1024))[tid] = z4;
    for (int t = tid; t < 192; t += 256)
        ((float4*)(hb + (size_t)n0 * HS))[t] = z4;
    int lofs = (c16 * 4 + q) * 8;
    zgemm_stage(xa_s, 136, 33, 33, w, c16, q, lofs, naA, W1hi, W1lo, part_s);
    __syncthreads();
    for (int t = tid; t < 1024; t += 256) {
        int row = t >> 6, col = t & 63;
        float v = part_s[0][row][col] + part_s[1][row][col] + part_s[2][row][col] +
                  part_s[3][row][col] + bu1_l[col];
        u1_s[row * 72 + col] = __float2bfloat16(silu_f(v));
    }
    __syncthreads();
    zgemm_stage(u1_s, 72, 16, 16, w, c16, q, lofs, naA, W2hi_, W2lo_, part_s);
    __syncthreads();
    for (int t = tid; t < 1024; t += 256) {
        int row = t >> 6, col = t & 63;
        float v = part_s[0][row][col] + part_s[1][row][col] + part_s[2][row][col] +
                  part_s[3][row][col] + bu2_l[col];
        int n = n0 + row;
        float hn = h[(size_t)n * 64 + col] + v;
        h[(size_t)n * 64 + col] = hn;
        hb[(size_t)n * HS + (col / 17) * 24 + col % 17] = __float2bfloat16(hn);
    }
    if (tid < 16) hb[(size_t)(n0 + tid) * HS + 85] = __float2bfloat16(anf[n0 + tid]);
}

// ---------------- K6: fused node update (layer 1) + prepool -> p2 ----------------
__global__ __launch_bounds__(256) void k_upd_prepool(
        const float* __restrict__ h_in, const float* __restrict__ anf,
        const float* __restrict__ na, const float* __restrict__ agg_in,
        const __hip_bfloat16* __restrict__ W1hi, const __hip_bfloat16* __restrict__ W1lo,
        const float* __restrict__ bu1_l,
        const __hip_bfloat16* __restrict__ W2hi_, const __hip_bfloat16* __restrict__ W2lo_,
        const float* __restrict__ bu2_l,
        const __hip_bfloat16* __restrict__ Wp1hi, const __hip_bfloat16* __restrict__ Wp1lo,
        const float* __restrict__ bp1,
        const __hip_bfloat16* __restrict__ Wp2hi, const __hip_bfloat16* __restrict__ Wp2lo,
        const float* __restrict__ bp2,
        float* __restrict__ p2) {
    __shared__ __align__(16) __hip_bfloat16 xa_s[16 * 136];
    __shared__ __align__(16) __hip_bfloat16 u1_s[16 * 72];
    __shared__ __align__(16) __hip_bfloat16 x2_s[16 * 72];
    __shared__ float part_s[4][16][64];
    int tid = threadIdx.x;
    int w = tid >> 6, l = tid & 63;
    int n0 = blockIdx.x * 16;
    for (int idx = tid; idx < 16 * 132; idx += 256) {
        int r = idx / 132, c = idx % 132;
        int n = n0 + r;
        float v;
        if (c < 64) v = h_in[(size_t)n * 64 + c];
        else if (c == 64) v = anf[n];
        else if (c < 129) v = agg_in[(size_t)n * 64 + (c - 65)];
        else v = 0.f;
        xa_s[r * 136 + c] = __float2bfloat16(v);
    }
    int c16 = l & 15, q = l >> 4;
    float naA[8];
#pragma unroll
    for (int j = 0; j < 8; ++j) naA[j] = na[(size_t)(n0 + c16) * 8 + j];
    __syncthreads();
    int lofs = (c16 * 4 + q) * 8;
    zgemm_stage(xa_s, 136, 33, 33, w, c16, q, lofs, naA, W1hi, W1lo, part_s);
    __syncthreads();
    for (int t = tid; t < 1024; t += 256) {
        int row = t >> 6, col = t & 63;
        float v = part_s[0][row][col] + part_s[1][row][col] + part_s[2][row][col] +
                  part_s[3][row][col] + bu1_l[col];
        u1_s[row * 72 + col] = __float2bfloat16(silu_f(v));
    }
    __syncthreads();
    zgemm_stage(u1_s, 72, 16, 16, w, c16, q, lofs, naA, W2hi_, W2lo_, part_s);
    __syncthreads();
    for (int t = tid; t < 1024; t += 256) {
        int row = t >> 6, col = t & 63;
        float v = part_s[0][row][col] + part_s[1][row][col] + part_s[2][row][col] +
                  part_s[3][row][col] + bu2_l[col];
        float hn = h_in[(size_t)(n0 + row) * 64 + col] + v;
        x2_s[row * 72 + col] = __float2bfloat16(hn);
    }
    __syncthreads();
    zgemm_stage(x2_s, 72, 16, 16, w, c16, q, lofs, naA, Wp1hi, Wp1lo, part_s);
    __syncthreads();
    for (int t = tid; t < 1024; t += 256) {
        int row = t >> 6, col = t & 63;
        float v = part_s[0][row][col] + part_s[1][row][col] + part_s[2][row][col] +
                  part_s[3][row][col] + bp1[col];
        u1_s[row * 72 + col] = __float2bfloat16(silu_f(v));
    }
    __syncthreads();
    zgemm_stage(u1_s, 72, 16, 16, w, c16, q, lofs, naA, Wp2hi, Wp2lo, part_s);
    __syncthreads();
    for (int t = tid; t < 1024; t += 256) {
        int row = t >> 6, col = t & 63;
        float v = part_s[0][row][col] + part_s[1][row][col] + part_s[2][row][col] +
                  part_s[3][row][col] + bp2[col];
        p2[(size_t)(n0 + row) * 64 + col] = v;
    }
}

// ---------------- K_pool ----------------
__global__ __launch_bounds__(256) void k_pool(
        const float* __restrict__ p2, const int* __restrict__ batch,
        float* __restrict__ partial_p, float* __restrict__ partial_cnt) {
    __shared__ float acc_s[16 * 64];
    __shared__ float cnt_s[16];
    int tid = threadIdx.x;
    for (int idx = tid; idx < 1024; idx += 256) acc_s[idx] = 0.f;
    if (tid < 16) cnt_s[tid] = 0.f;
    __syncthreads();
    int w = tid >> 6, k = tid & 63;
    int base = blockIdx.x * 125;
    for (int i = 0; i < 32; ++i) {
        int nl = i * 4 + w;
        if (nl < 125) {
            int n = base + nl;
            int b = batch[n];
            atomicAdd(&acc_s[b * 64 + k], p2[(size_t)n * 64 + k]);
            if (k == 0) atomicAdd(&cnt_s[b], 1.0f);
        }
    }
    __syncthreads();
    for (int idx = tid; idx < 1024; idx += 256)
        partial_p[(size_t)blockIdx.x * 1024 + idx] = acc_s[idx];
    if (tid < 16) partial_cnt[blockIdx.x * 16 + tid] = cnt_s[tid];
}

// ---------------- K7: reduce partials, mean, final MLP ----------------
__global__ __launch_bounds__(1024) void k_final(
        const float* __restrict__ partial_p, const float* __restrict__ partial_cnt,
        const float* __restrict__ Wq1, const float* __restrict__ bq1,
        const float* __restrict__ Wq2, const float* __restrict__ bq2,
        float* __restrict__ out) {
    __shared__ float g[16][64];
    int b = threadIdx.x >> 6, k = threadIdx.x & 63;
    float s = 0.f, cc = 0.f;
    for (int c = 0; c < POOL_CHUNKS; ++c) s += partial_p[(size_t)c * 1024 + b * 64 + k];
    for (int c = 0; c < POOL_CHUNKS; ++c) cc += partial_cnt[c * 16 + b];
    g[b][k] = s / fmaxf(cc, 1.0f);
    __syncthreads();
    float acc = bq1[k];
#pragma unroll
    for (int i = 0; i < 64; ++i) acc = fmaf(g[b][i], Wq1[i * 64 + k], acc);
    float v = silu_f(acc) * Wq2[k];
#pragma unroll
    for (int off = 32; off > 0; off >>= 1) v += __shfl_down(v, off, 64);
    if (k == 0) out[b] = v + bq2[0];
}

extern "C" void kernel_launch(void* const* d_in, const int* in_sizes, int n_in,
                              void* d_out, int out_size, void* d_ws, size_t ws_size,
                              hipStream_t stream) {
    const float* x    = (const float*)d_in[0];
    const int*   eidx = (const int*)  d_in[1];
    const float* ea   = (const float*)d_in[2];
    const float* na   = (const float*)d_in[3];
    const float* amf  = (const float*)d_in[4];
    const float* anf  = (const float*)d_in[5];
    const int*   batch= (const int*)  d_in[6];
    const float* W_emb= (const float*)d_in[7];
    const float* b_emb= (const float*)d_in[8];
    const float* Wm1  = (const float*)d_in[9];
    const float* bm1  = (const float*)d_in[10];
    const float* Wm2  = (const float*)d_in[11];
    const float* bm2  = (const float*)d_in[12];
    const float* Wu1  = (const float*)d_in[13];
    const float* bu1  = (const float*)d_in[14];
    const float* Wu2  = (const float*)d_in[15];
    const float* bu2  = (const float*)d_in[16];
    const float* Wp1  = (const float*)d_in[17];
    const float* bp1  = (const float*)d_in[18];
    const float* Wp2  = (const float*)d_in[19];
    const float* bp2  = (const float*)d_in[20];
    const float* Wq1  = (const float*)d_in[21];
    const float* bq1  = (const float*)d_in[22];
    const float* Wq2  = (const float*)d_in[23];
    const float* bq2  = (const float*)d_in[24];

    float* ws = (float*)d_ws;
    float* h      = ws;                            // N*64
    float* agg    = h + (size_t)N * 64;            // N*64
    float* p2     = agg + (size_t)N * 64;          // N*64
    float* part_p = p2 + (size_t)N * 64;           // 80*1024
    float* part_c = part_p + POOL_CHUNKS * 1024;   // 80*16
    float* fend   = part_c + POOL_CHUNKS * 16;
    __hip_bfloat16* hb     = (__hip_bfloat16*)fend;          // N*96
    __hip_bfloat16* W2hi   = hb + (size_t)N * HS;            // 2*32768
    __hip_bfloat16* Wm1zhi = W2hi + 65536;                   // 2*71680
    __hip_bfloat16* Wu1hi  = Wm1zhi + 143360;                // 2*67584
    __hip_bfloat16* Wu1lo  = Wu1hi + 135168;
    __hip_bfloat16* Wu2hi  = Wu1lo + 135168;                 // 2*32768
    __hip_bfloat16* Wu2lo  = Wu2hi + 65536;
    __hip_bfloat16* Wp1hi  = Wu2lo + 65536;                  // 32768
    __hip_bfloat16* Wp1lo  = Wp1hi + 32768;
    __hip_bfloat16* Wp2hi  = Wp1lo + 32768;
    __hip_bfloat16* Wp2lo  = Wp2hi + 32768;
    int* hist   = (int*)(Wp2lo + 32768);                     // N
    int* cursor = hist + N;                                  // N
    int* dstS   = cursor + N;                                // E
    float4* recs = (float4*)(dstS + E);                      // E * 3 float4 (48B/edge)

    // mega pre-kernel: all weight reorders + hist zero + embed(+agg/hb init)
    k_pre<<<PB_TOTAL, 256, 0, stream>>>(
        Wm2, W2hi, Wm1, Wm1zhi, Wu1, Wu1hi, Wu1lo, Wu2, Wu2hi, Wu2lo,
        Wp1, Wp1hi, Wp1lo, Wp2, Wp2hi, Wp2lo, hist,
        x, anf, na, W_emb, b_emb, h, hb, agg);

    // dst-sort + materialize sorted edge records (reused by both edge dispatches)
    k_hist<<<(E + 255) / 256, 256, 0, stream>>>(eidx, hist);
    k_scan<<<1, 1024, 0, stream>>>(hist, cursor);
    k_scatter_sort<<<(E + 255) / 256, 256, 0, stream>>>(eidx, ea, amf, cursor, dstS, recs);

    k_edge<<<E / 128, 256, 0, stream>>>(recs, dstS, hb,
                                        Wm1zhi, bm1, W2hi, bm2, agg);
    k_upd_hb<<<625, 256, 0, stream>>>(h, anf, na, agg,
                                      Wu1hi, Wu1lo, bu1,
                                      Wu2hi, Wu2lo, bu2,
                                      h, hb, agg);
    k_edge<<<E / 128, 256, 0, stream>>>(recs, dstS, hb,
                                        Wm1zhi + 71680, bm1 + 64,
                                        W2hi + 32768, bm2 + 64, agg);
    k_upd_prepool<<<625, 256, 0, stream>>>(h, anf, na, agg,
                                           Wu1hi + 67584, Wu1lo + 67584, bu1 + 64,
                                           Wu2hi + 32768, Wu2lo + 32768, bu2 + 64,
                                           Wp1hi, Wp1lo, bp1, Wp2hi, Wp2lo, bp2, p2);
    k_pool<<<POOL_CHUNKS, 256, 0, stream>>>(p2, batch, part_p, part_c);
    k_final<<<1, 1024, 0, stream>>>(part_p, part_c, Wq1, bq1, Wq2, bq2, (float*)d_out);
}

// Round 9
// 331.838 us; speedup vs baseline: 1.1710x; 1.1180x over previous
//
#include <hip/hip_runtime.h>
#include <hip/hip_bf16.h>
#include <math.h>

// Problem constants
constexpr int N = 10000;
constexpr int E = 160000;
constexpr int B = 16;
constexpr int POOL_CHUNKS = 80;   // 80 * 125 = 10000
constexpr int MS = 72;            // m_s row stride (bf16), wave-local
constexpr int HS = 96;            // hb row stride: 4 q-sections x 24 (17 used + pad)

typedef short bf16x8 __attribute__((ext_vector_type(8)));
typedef short bf16x4 __attribute__((ext_vector_type(4)));
typedef float f32x4 __attribute__((ext_vector_type(4)));

__device__ __forceinline__ float silu_f(float x) {
    return x / (1.0f + __expf(-x));
}
__device__ __forceinline__ float bf2f(short s) {
    union { unsigned u; float f; } c; c.u = (unsigned)(unsigned short)s << 16; return c.f;
}
// async global->LDS DMA, 16B/lane. LDS dest: wave-uniform base + lane*16 (linear).
__device__ __forceinline__ void gload_lds16(const void* g, void* l) {
    __builtin_amdgcn_global_load_lds(
        (const __attribute__((address_space(1))) void*)g,
        (__attribute__((address_space(3))) void*)l, 16, 0, 0);
}

// ---------------- weight reorder bodies (q-major i-mapping) ----------------
__device__ __forceinline__ void w2_body(
        int idx, const float* __restrict__ Wsrc,
        __hip_bfloat16* __restrict__ Whi, __hip_bfloat16* __restrict__ Wlo) {
    int l = idx >> 15;
    int rem = idx & 32767;
    int kk = rem >> 11;
    int nt = (rem >> 9) & 3;
    int c  = (rem >> 5) & 15;
    int q  = (rem >> 3) & 3;
    int j  = rem & 7;
    int i = q * 16 + kk;
    int k = nt * 16 + c;
    float wv = Wsrc[(size_t)l * 32768 + i * 512 + j * 64 + k];
    __hip_bfloat16 hi = __float2bfloat16(wv);
    Whi[idx] = hi;
    Wlo[idx] = __float2bfloat16(wv - __bfloat162float(hi));
}

__device__ __forceinline__ void w2h_body(
        int idx, const float* __restrict__ Wsrc, __hip_bfloat16* __restrict__ Whi) {
    int l = idx >> 15;
    int rem = idx & 32767;
    int kk = rem >> 11;
    int nt = (rem >> 9) & 3;
    int c  = (rem >> 5) & 15;
    int q  = (rem >> 3) & 3;
    int j  = rem & 7;
    int i = q * 16 + kk;
    int k = nt * 16 + c;
    Whi[idx] = __float2bfloat16(Wsrc[(size_t)l * 32768 + i * 512 + j * 64 + k]);
}

__device__ __forceinline__ void wu1_body(
        int idx, const float* __restrict__ Wu1,
        __hip_bfloat16* __restrict__ Whi, __hip_bfloat16* __restrict__ Wlo) {
    int l = idx / 67584;
    int rem = idx % 67584;
    int kk = rem / 2048;          // 0..32
    int r2 = rem % 2048;
    int nt = (r2 >> 9) & 3;
    int c  = (r2 >> 5) & 15;
    int q  = (r2 >> 3) & 3;
    int j  = r2 & 7;
    int i = q * 33 + kk;          // 0..131
    float wv = (i < 129) ? Wu1[(size_t)l * 129 * 512 + i * 512 + j * 64 + nt * 16 + c] : 0.f;
    __hip_bfloat16 hi = __float2bfloat16(wv);
    Whi[idx] = hi;
    Wlo[idx] = __float2bfloat16(wv - __bfloat162float(hi));
}

__device__ __forceinline__ void wm1z_body(
        int idx, const float* __restrict__ Wm1, __hip_bfloat16* __restrict__ Whi) {
    int l = idx / 71680;
    int rem = idx % 71680;
    int kkn = rem >> 9;          // 0..139
    int off = rem & 511;
    int kk = kkn >> 2;
    int nt = kkn & 3;
    int c16 = off >> 5;
    int q = (off >> 3) & 3;
    int j = off & 7;
    int k = nt * 16 + c16;
    int wi = -1;
    if (kk < 17) { int i = q * 17 + kk; if (i <= 64) wi = i; }
    else if (kk < 34) { int s = q * 17 + (kk - 17); if (s <= 64) wi = 65 + s; }
    else { if (q == 0) wi = 130; }
    float wv = (wi >= 0) ? Wm1[((size_t)l * 131 + wi) * 512 + j * 64 + k] : 0.f;
    Whi[idx] = __float2bfloat16(wv);
}

// ---------------- mega pre-kernel: all weight reorders + hist zero + embed ----------------
constexpr int PB_W2H  = 0;                 // 256 blocks: Wm2 -> W2hi
constexpr int PB_WM1Z = PB_W2H  + 256;     // 560
constexpr int PB_WU1  = PB_WM1Z + 560;     // 528
constexpr int PB_WU2  = PB_WU1  + 528;     // 256
constexpr int PB_WP1  = PB_WU2  + 256;     // 128
constexpr int PB_WP2  = PB_WP1  + 128;     // 128
constexpr int PB_ZERO = PB_WP2  + 128;     // 40
constexpr int PB_EMB  = PB_ZERO + 40;      // 625
constexpr int PB_TOTAL= PB_EMB  + 625;     // 2521

__global__ __launch_bounds__(256) void k_pre(
        const float* __restrict__ Wm2, __hip_bfloat16* __restrict__ W2hi,
        const float* __restrict__ Wm1, __hip_bfloat16* __restrict__ Wm1zhi,
        const float* __restrict__ Wu1w, __hip_bfloat16* __restrict__ Wu1hi, __hip_bfloat16* __restrict__ Wu1lo,
        const float* __restrict__ Wu2w, __hip_bfloat16* __restrict__ Wu2hi, __hip_bfloat16* __restrict__ Wu2lo,
        const float* __restrict__ Wp1w, __hip_bfloat16* __restrict__ Wp1hi, __hip_bfloat16* __restrict__ Wp1lo,
        const float* __restrict__ Wp2w, __hip_bfloat16* __restrict__ Wp2hi, __hip_bfloat16* __restrict__ Wp2lo,
        int* __restrict__ hist,
        const float* __restrict__ x, const float* __restrict__ anf,
        const float* __restrict__ na, const float* __restrict__ W_emb,
        const float* __restrict__ b_emb,
        float* __restrict__ h, __hip_bfloat16* __restrict__ hb, float* __restrict__ agg) {
    __shared__ float xs[16][18];
    __shared__ float na_s[16][8];
    int tid = threadIdx.x;
    int bx = blockIdx.x;
    if (bx < PB_WM1Z) {
        w2h_body((bx - PB_W2H) * 256 + tid, Wm2, W2hi);
    } else if (bx < PB_WU1) {
        wm1z_body((bx - PB_WM1Z) * 256 + tid, Wm1, Wm1zhi);
    } else if (bx < PB_WU2) {
        wu1_body((bx - PB_WU1) * 256 + tid, Wu1w, Wu1hi, Wu1lo);
    } else if (bx < PB_WP1) {
        w2_body((bx - PB_WU2) * 256 + tid, Wu2w, Wu2hi, Wu2lo);
    } else if (bx < PB_WP2) {
        w2_body((bx - PB_WP1) * 256 + tid, Wp1w, Wp1hi, Wp1lo);
    } else if (bx < PB_ZERO) {
        w2_body((bx - PB_WP2) * 256 + tid, Wp2w, Wp2hi, Wp2lo);
    } else if (bx < PB_EMB) {
        int i = (bx - PB_ZERO) * 256 + tid;
        if (i < N) hist[i] = 0;
    } else {
        // ---- embed: h fp32 + hb (q-sectioned) + agg zero ----
        int eb = bx - PB_EMB;
        int w = tid >> 6, l = tid & 63;
        int n0 = eb * 16;
        {
            int r = tid >> 4, c = tid & 15;
            xs[r][c] = x[(size_t)(n0 + r) * 16 + c];
        }
        if (tid < 16) xs[tid][16] = anf[n0 + tid];
        if (tid < 128) na_s[tid >> 3][tid & 7] = na[(size_t)n0 * 8 + tid];
        float4 z4 = {0.f, 0.f, 0.f, 0.f};
        ((float4*)(agg + (size_t)eb * 1024))[tid] = z4;
        for (int t = tid; t < 192; t += 256)
            ((float4*)(hb + (size_t)n0 * HS))[t] = z4;
        __syncthreads();
        float acc[4];
#pragma unroll
        for (int t = 0; t < 4; ++t) acc[t] = b_emb[l];
        for (int i = 0; i < 17; ++i) {
#pragma unroll
            for (int j = 0; j < 8; ++j) {
                float wv = W_emb[(i * 8 + j) * 64 + l];
#pragma unroll
                for (int t = 0; t < 4; ++t) {
                    int nn = w * 4 + t;
                    acc[t] = fmaf(xs[nn][i] * na_s[nn][j], wv, acc[t]);
                }
            }
        }
        int slot = (l / 17) * 24 + l % 17;
#pragma unroll
        for (int t = 0; t < 4; ++t) {
            int n = n0 + w * 4 + t;
            h[(size_t)n * 64 + l] = acc[t];
            hb[(size_t)n * HS + slot] = __float2bfloat16(acc[t]);
        }
        if (tid < 16) hb[(size_t)(n0 + tid) * HS + 85] = __float2bfloat16(xs[tid][16]);
    }
}

// ---------------- edge sort by dst: histogram / scan / scatter+materialize ----------------
__global__ __launch_bounds__(256) void k_hist(
        const int* __restrict__ eidx, int* __restrict__ hist) {
    int e = blockIdx.x * 256 + threadIdx.x;
    if (e < E) atomicAdd(&hist[eidx[E + e]], 1);
}

// single-block exclusive scan over N=10000 bins -> cursor
__global__ __launch_bounds__(1024) void k_scan(
        const int* __restrict__ hist, int* __restrict__ cursor) {
    __shared__ int wsum[16];
    int t = threadIdx.x;
    int base = t * 10;
    int loc[10];
    int s = 0;
#pragma unroll
    for (int i = 0; i < 10; ++i) {
        int v = (base + i < N) ? hist[base + i] : 0;
        loc[i] = s;
        s += v;
    }
    int lane = t & 63, w = t >> 6;
    int incl = s;
    for (int off = 1; off < 64; off <<= 1) {
        int u = __shfl_up(incl, off, 64);
        if (lane >= off) incl += u;
    }
    if (lane == 63) wsum[w] = incl;
    __syncthreads();
    if (t == 0) {
        int a = 0;
        for (int i2 = 0; i2 < 16; ++i2) { int v = wsum[i2]; wsum[i2] = a; a += v; }
    }
    __syncthreads();
    int excl = incl - s + wsum[w];
#pragma unroll
    for (int i = 0; i < 10; ++i) {
        int p = base + i;
        if (p < N) cursor[p] = excl + loc[i];
    }
}

// scatter into dst-sorted records (coalesced reads; 48B record = 1-2 line touches/edge)
__global__ __launch_bounds__(256) void k_scatter_sort(
        const int* __restrict__ eidx, const float* __restrict__ ea,
        const float* __restrict__ amf, int* __restrict__ cursor,
        int* __restrict__ dstS, float4* __restrict__ recs) {
    int e = blockIdx.x * 256 + threadIdx.x;
    if (e < E) {
        int d = eidx[E + e];
        int p = atomicAdd(&cursor[d], 1);
        dstS[p] = d;
        float4 a0 = ((const float4*)ea)[(size_t)e * 2];
        float4 a1 = ((const float4*)ea)[(size_t)e * 2 + 1];
        float4 r0 = {__int_as_float(eidx[e]), amf[e], a0.x, a0.y};
        float4 r1 = {a0.z, a0.w, a1.x, a1.y};
        float4 r2 = {a1.z, a1.w, 0.f, 0.f};
        recs[(size_t)p * 3 + 0] = r0;
        recs[(size_t)p * 3 + 1] = r1;
        recs[(size_t)p * 3 + 2] = r2;
    }
}

// ---------------- device helper: one z-GEMM stage (hi/lo), 4 waves split K, q-major x ----------------
__device__ __forceinline__ void zgemm_stage(
        const __hip_bfloat16* xsrc, int xstride, int kkmax, int Lq,
        int w, int c16, int q, int lofs, const float* naA,
        const __hip_bfloat16* __restrict__ Whi, const __hip_bfloat16* __restrict__ Wlo,
        float (*part_s)[16][64]) {
    f32x4 zero4 = {0.f, 0.f, 0.f, 0.f};
    f32x4 acc[4];
#pragma unroll
    for (int nt = 0; nt < 4; ++nt) acc[nt] = zero4;
    for (int kk = w; kk < kkmax; kk += 4) {
        bf16x8 bh[4], bl[4];
#pragma unroll
        for (int nt = 0; nt < 4; ++nt) {
            int off = (kk * 4 + nt) * 512 + lofs;
            bh[nt] = *(const bf16x8*)(Whi + off);
            bl[nt] = *(const bf16x8*)(Wlo + off);
        }
        float mv = __bfloat162float(xsrc[c16 * xstride + q * Lq + kk]);
        union { bf16x8 v; __hip_bfloat16 hx[8]; } au;
#pragma unroll
        for (int j = 0; j < 8; ++j) au.hx[j] = __float2bfloat16(mv * naA[j]);
#pragma unroll
        for (int nt = 0; nt < 4; ++nt) {
            acc[nt] = __builtin_amdgcn_mfma_f32_16x16x32_bf16(au.v, bh[nt], acc[nt], 0, 0, 0);
            acc[nt] = __builtin_amdgcn_mfma_f32_16x16x32_bf16(au.v, bl[nt], acc[nt], 0, 0, 0);
        }
    }
#pragma unroll
    for (int nt = 0; nt < 4; ++nt)
#pragma unroll
        for (int r = 0; r < 4; ++r) part_s[w][q * 4 + r][nt * 16 + c16] = acc[nt][r];
}

// ---------------- K3: edge kernel — LDS-staged weights via async DMA (global_load_lds) ----------------
// r7/r8: reg-staged LDS dbuf worked but the allocator spilled ~16 regs (WRITE 25-26MB) and
// source-level liveness cuts didn't clear it. Fix: stage with __builtin_amdgcn_global_load_lds
// (width=16) — ZERO staging VGPRs, zero ds_writes. The compiler's mandatory s_waitcnt vmcnt(0)
// before each s_barrier (guide §5) makes the existing one-barrier-per-chunk schedule correct
// with no extra sync: issue chunk c+1's DMA right after the barrier that publishes chunk c,
// consume chunk c, barrier (drains own DMA, syncs all waves), repeat. Linear LDS layout on
// both sides (rule #21). LDS 51.7KB -> 3 blocks/CU = 12 waves/CU ~= measured occupancy.
__global__ __launch_bounds__(256, 3) void k_edge(
        const float4* __restrict__ recs, const int* __restrict__ dstS,
        const __hip_bfloat16* __restrict__ hb,
        const __hip_bfloat16* __restrict__ W1hi, const float* __restrict__ bm1_l,
        const __hip_bfloat16* __restrict__ W2hi,
        const float* __restrict__ bm2_l, float* __restrict__ agg) {
    __shared__ __align__(16) __hip_bfloat16 wbuf[2][8192];   // 2 x 16KB weight chunks
    // per-wave private 4608B region: m_s [32][72] bf16; m2 chunk [16][66] f32 overlaid
    __shared__ __align__(16) char smem_u[4 * 4608];          // 18432 B
    __shared__ int dst_s[128];
    int tid = threadIdx.x;
    int l = tid & 63, w = tid >> 6;
    int e0 = blockIdx.x * 128;
    __hip_bfloat16* m_s = (__hip_bfloat16*)(smem_u + w * 4608);
    float* m2 = (float*)(smem_u + w * 4608);

    if (l < 32) dst_s[w * 32 + l] = dstS[e0 + w * 32 + l];

    int c16 = l & 15, q = l >> 4;
    int e0w = w * 32;
    float eaA[2][8], amfA[2];
    int dL[2], sL[2];
#pragma unroll
    for (int mt = 0; mt < 2; ++mt) {
        int e = e0 + e0w + mt * 16 + c16;
        float4 r0 = recs[(size_t)e * 3];
        float4 r1 = recs[(size_t)e * 3 + 1];
        float4 r2 = recs[(size_t)e * 3 + 2];
        sL[mt] = __float_as_int(r0.x);
        amfA[mt] = r0.y;
        eaA[mt][0] = r0.z; eaA[mt][1] = r0.w;
        eaA[mt][2] = r1.x; eaA[mt][3] = r1.y; eaA[mt][4] = r1.z; eaA[mt][5] = r1.w;
        eaA[mt][6] = r2.x; eaA[mt][7] = r2.y;
        dL[mt] = dstS[e];
    }
    float bR1[4], bR2[4];
#pragma unroll
    for (int nt = 0; nt < 4; ++nt) {
        bR1[nt] = bm1_l[nt * 16 + c16];
        bR2[nt] = bm2_l[nt * 16 + c16];
    }
    int lofs = (c16 * 4 + q) * 8;
    f32x4 zero4 = {0.f, 0.f, 0.f, 0.f};

    // async-DMA staging of one 16KB chunk (nk*4KB): per round r, wave w covers 1KB.
    // global addr is per-lane; LDS base is wave-uniform (+ lane*16 implicit).
    auto stage = [&](const __hip_bfloat16* src, __hip_bfloat16* dbuf, int nk) {
        const char* g = (const char*)src;
        char* lb = (char*)dbuf;
#pragma unroll
        for (int r = 0; r < 4; ++r)
            if (r < nk)
                gload_lds16(g + (size_t)(r * 256 + w * 64 + l) * 16,
                            lb + (r * 256 + w * 64) * 16);
    };

    // gather D-side fragments only (S-side deferred to c==3)
    bf16x4 xD[2][5];
#pragma unroll
    for (int mt = 0; mt < 2; ++mt) {
        const __hip_bfloat16* bd = hb + (size_t)dL[mt] * HS + q * 24;
#pragma unroll
        for (int t = 0; t < 5; ++t)
            xD[mt][t] = *(const bf16x4*)(bd + t * 4);
    }

    // issue chunk 0 DMA (drained by the first in-loop barrier)
    stage(W1hi, wbuf[0], 4);

    f32x4 acc[2][4];
#pragma unroll
    for (int mt = 0; mt < 2; ++mt)
#pragma unroll
        for (int nt = 0; nt < 4; ++nt) acc[mt][nt] = zero4;
    bf16x4 xS[2][5];    // loaded at c==3
    bf16x4 mR[2][4];    // loaded at c==8

    // 13 chunks: c 0..8 = W1 (8x4kk + 1x3kk), c 9..12 = W2 (4x4kk)
#pragma unroll
    for (int c = 0; c < 13; ++c) {
        __syncthreads();   // drains each wave's own DMA (vmcnt(0)) then syncs -> buf[c&1] ready
        // issue next-chunk DMA into the other buffer (consumed after the NEXT barrier)
        if (c + 1 < 13) {
            const __hip_bfloat16* nsrc = (c + 1 < 9) ? (W1hi + (c + 1) * 8192)
                                                     : (W2hi + (c + 1 - 9) * 8192);
            stage(nsrc, wbuf[(c + 1) & 1], (c + 1 == 8) ? 3 : 4);
        }
        if (c == 3) {
            // prefetch S-side gathers (first used in chunk 4); xD is nearly dead by then
#pragma unroll
            for (int mt = 0; mt < 2; ++mt) {
                const __hip_bfloat16* bs = hb + (size_t)sL[mt] * HS + q * 24;
#pragma unroll
                for (int t = 0; t < 5; ++t)
                    xS[mt][t] = *(const bf16x4*)(bs + t * 4);
            }
        }
        // consume chunk c from wbuf[c&1]
        const __hip_bfloat16* wb = wbuf[c & 1];
        if (c < 9) {
            const int nkk = (c == 8) ? 3 : 4;
#pragma unroll
            for (int kkl = 0; kkl < 4; ++kkl) {
                if (kkl < nkk) {
                    const int u = c * 4 + kkl;      // 0..34
                    bf16x8 bh[4];
#pragma unroll
                    for (int nt = 0; nt < 4; ++nt)
                        bh[nt] = *(const bf16x8*)&wb[(kkl * 4 + nt) * 512 + lofs];
#pragma unroll
                    for (int mt = 0; mt < 2; ++mt) {
                        float xv;
                        if (u < 17)      xv = bf2f(xD[mt][u >> 2][u & 3]);
                        else if (u < 34) { const int s = u - 17; xv = bf2f(xS[mt][s >> 2][s & 3]); }
                        else             xv = (q == 0) ? amfA[mt] : 0.f;
                        union { bf16x8 v; __hip_bfloat16 hx[8]; } au;
#pragma unroll
                        for (int j = 0; j < 8; ++j) au.hx[j] = __float2bfloat16(xv * eaA[mt][j]);
#pragma unroll
                        for (int nt = 0; nt < 4; ++nt)
                            acc[mt][nt] = __builtin_amdgcn_mfma_f32_16x16x32_bf16(au.v, bh[nt], acc[mt][nt], 0, 0, 0);
                    }
                }
            }
        } else {
#pragma unroll
            for (int kkl = 0; kkl < 4; ++kkl) {
                const int kk = (c - 9) * 4 + kkl;   // 0..15
                bf16x8 bh[4];
#pragma unroll
                for (int nt = 0; nt < 4; ++nt)
                    bh[nt] = *(const bf16x8*)&wb[(kkl * 4 + nt) * 512 + lofs];
#pragma unroll
                for (int mt = 0; mt < 2; ++mt) {
                    float mv = bf2f(mR[mt][kk >> 2][kk & 3]);
                    union { bf16x8 v; __hip_bfloat16 hx[8]; } au;
#pragma unroll
                    for (int j = 0; j < 8; ++j) au.hx[j] = __float2bfloat16(mv * eaA[mt][j]);
#pragma unroll
                    for (int nt = 0; nt < 4; ++nt)
                        acc[mt][nt] = __builtin_amdgcn_mfma_f32_16x16x32_bf16(au.v, bh[nt], acc[mt][nt], 0, 0, 0);
                }
            }
        }
        if (c == 8) {
            // phase-1 epilogue: drain acc -> m_s, read transposed fragments, re-zero acc
#pragma unroll
            for (int mt = 0; mt < 2; ++mt)
#pragma unroll
                for (int nt = 0; nt < 4; ++nt) {
                    int kd = nt * 16 + c16;
                    float bias = bR1[nt];
#pragma unroll
                    for (int r = 0; r < 4; ++r) {
                        int el = mt * 16 + q * 4 + r;
                        m_s[el * MS + kd] = __float2bfloat16(silu_f(bias + acc[mt][nt][r]));
                    }
                }
#pragma unroll
            for (int mt = 0; mt < 2; ++mt)
#pragma unroll
                for (int t = 0; t < 4; ++t)
                    mR[mt][t] = *(const bf16x4*)&m_s[(mt * 16 + c16) * MS + q * 16 + t * 4];
            // m2 (float) writes later alias m_s (bf16) bytes — forbid TBAA reordering
            asm volatile("" ::: "memory");
#pragma unroll
            for (int mt = 0; mt < 2; ++mt)
#pragma unroll
                for (int nt = 0; nt < 4; ++nt) acc[mt][nt] = zero4;   // reuse for phase 2
        }
    }

    // chunked epilogue: per mt-chunk write 16 rows of m2 (own region), run-length reduce, atomics.
    // runs spanning chunk boundaries just produce one extra atomic — still exact.
#pragma unroll
    for (int mt = 0; mt < 2; ++mt) {
#pragma unroll
        for (int nt = 0; nt < 4; ++nt) {
            int kd = nt * 16 + c16;
            float bias = bR2[nt];
#pragma unroll
            for (int r = 0; r < 4; ++r)
                m2[(q * 4 + r) * 66 + kd] = silu_f(bias + acc[mt][nt][r]);
        }
        int rb = w * 32 + mt * 16;
        float run = 0.f;
        int cur_d = dst_s[rb];
        for (int i = 0; i < 16; ++i) {
            int d = dst_s[rb + i];                 // wave-uniform
            if (d != cur_d) {
                atomicAdd(&agg[(size_t)cur_d * 64 + l], run);
                run = 0.f;
                cur_d = d;
            }
            run += m2[i * 66 + l];
        }
        atomicAdd(&agg[(size_t)cur_d * 64 + l], run);
        asm volatile("" ::: "memory");             // chunk reads complete before next chunk overwrite
    }
}

// ---------------- K4: node update + write h/hb + agg zero ----------------
__global__ __launch_bounds__(256) void k_upd_hb(
        const float* __restrict__ h_in, const float* __restrict__ anf,
        const float* __restrict__ na, const float* __restrict__ agg_in,
        const __hip_bfloat16* __restrict__ W1hi, const __hip_bfloat16* __restrict__ W1lo,
        const float* __restrict__ bu1_l,
        const __hip_bfloat16* __restrict__ W2hi_, const __hip_bfloat16* __restrict__ W2lo_,
        const float* __restrict__ bu2_l,
        float* __restrict__ h, __hip_bfloat16* __restrict__ hb, float* __restrict__ agg) {
    __shared__ __align__(16) __hip_bfloat16 xa_s[16 * 136];
    __shared__ __align__(16) __hip_bfloat16 u1_s[16 * 72];
    __shared__ float part_s[4][16][64];
    int tid = threadIdx.x;
    int w = tid >> 6, l = tid & 63;
    int n0 = blockIdx.x * 16;
    for (int idx = tid; idx < 16 * 132; idx += 256) {
        int r = idx / 132, c = idx % 132;
        int n = n0 + r;
        float v;
        if (c < 64) v = h_in[(size_t)n * 64 + c];
        else if (c == 64) v = anf[n];
        else if (c < 129) v = agg_in[(size_t)n * 64 + (c - 65)];
        else v = 0.f;
        xa_s[r * 136 + c] = __float2bfloat16(v);
    }
    int c16 = l & 15, q = l >> 4;
    float naA[8];
#pragma unroll
    for (int j = 0; j < 8; ++j) naA[j] = na[(size_t)(n0 + c16) * 8 + j];
    __syncthreads();
    float4 z4 = {0.f, 0.f, 0.f, 0.f};
    ((float4*)(agg + (size_t)blockIdx.x * 1024))[tid] = z4;
    for (int t = tid; t < 192; t += 256)
        ((float4*)(hb + (size_t)n0 * HS))[t] = z4;
    int lofs = (c16 * 4 + q) * 8;
    zgemm_stage(xa_s, 136, 33, 33, w, c16, q, lofs, naA, W1hi, W1lo, part_s);
    __syncthreads();
    for (int t = tid; t < 1024; t += 256) {
        int row = t >> 6, col = t & 63;
        float v = part_s[0][row][col] + part_s[1][row][col] + part_s[2][row][col] +
                  part_s[3][row][col] + bu1_l[col];
        u1_s[row * 72 + col] = __float2bfloat16(silu_f(v));
    }
    __syncthreads();
    zgemm_stage(u1_s, 72, 16, 16, w, c16, q, lofs, naA, W2hi_, W2lo_, part_s);
    __syncthreads();
    for (int t = tid; t < 1024; t += 256) {
        int row = t >> 6, col = t & 63;
        float v = part_s[0][row][col] + part_s[1][row][col] + part_s[2][row][col] +
                  part_s[3][row][col] + bu2_l[col];
        int n = n0 + row;
        float hn = h[(size_t)n * 64 + col] + v;
        h[(size_t)n * 64 + col] = hn;
        hb[(size_t)n * HS + (col / 17) * 24 + col % 17] = __float2bfloat16(hn);
    }
    if (tid < 16) hb[(size_t)(n0 + tid) * HS + 85] = __float2bfloat16(anf[n0 + tid]);
}

// ---------------- K6: fused node update (layer 1) + prepool -> p2 ----------------
__global__ __launch_bounds__(256) void k_upd_prepool(
        const float* __restrict__ h_in, const float* __restrict__ anf,
        const float* __restrict__ na, const float* __restrict__ agg_in,
        const __hip_bfloat16* __restrict__ W1hi, const __hip_bfloat16* __restrict__ W1lo,
        const float* __restrict__ bu1_l,
        const __hip_bfloat16* __restrict__ W2hi_, const __hip_bfloat16* __restrict__ W2lo_,
        const float* __restrict__ bu2_l,
        const __hip_bfloat16* __restrict__ Wp1hi, const __hip_bfloat16* __restrict__ Wp1lo,
        const float* __restrict__ bp1,
        const __hip_bfloat16* __restrict__ Wp2hi, const __hip_bfloat16* __restrict__ Wp2lo,
        const float* __restrict__ bp2,
        float* __restrict__ p2) {
    __shared__ __align__(16) __hip_bfloat16 xa_s[16 * 136];
    __shared__ __align__(16) __hip_bfloat16 u1_s[16 * 72];
    __shared__ __align__(16) __hip_bfloat16 x2_s[16 * 72];
    __shared__ float part_s[4][16][64];
    int tid = threadIdx.x;
    int w = tid >> 6, l = tid & 63;
    int n0 = blockIdx.x * 16;
    for (int idx = tid; idx < 16 * 132; idx += 256) {
        int r = idx / 132, c = idx % 132;
        int n = n0 + r;
        float v;
        if (c < 64) v = h_in[(size_t)n * 64 + c];
        else if (c == 64) v = anf[n];
        else if (c < 129) v = agg_in[(size_t)n * 64 + (c - 65)];
        else v = 0.f;
        xa_s[r * 136 + c] = __float2bfloat16(v);
    }
    int c16 = l & 15, q = l >> 4;
    float naA[8];
#pragma unroll
    for (int j = 0; j < 8; ++j) naA[j] = na[(size_t)(n0 + c16) * 8 + j];
    __syncthreads();
    int lofs = (c16 * 4 + q) * 8;
    zgemm_stage(xa_s, 136, 33, 33, w, c16, q, lofs, naA, W1hi, W1lo, part_s);
    __syncthreads();
    for (int t = tid; t < 1024; t += 256) {
        int row = t >> 6, col = t & 63;
        float v = part_s[0][row][col] + part_s[1][row][col] + part_s[2][row][col] +
                  part_s[3][row][col] + bu1_l[col];
        u1_s[row * 72 + col] = __float2bfloat16(silu_f(v));
    }
    __syncthreads();
    zgemm_stage(u1_s, 72, 16, 16, w, c16, q, lofs, naA, W2hi_, W2lo_, part_s);
    __syncthreads();
    for (int t = tid; t < 1024; t += 256) {
        int row = t >> 6, col = t & 63;
        float v = part_s[0][row][col] + part_s[1][row][col] + part_s[2][row][col] +
                  part_s[3][row][col] + bu2_l[col];
        float hn = h_in[(size_t)(n0 + row) * 64 + col] + v;
        x2_s[row * 72 + col] = __float2bfloat16(hn);
    }
    __syncthreads();
    zgemm_stage(x2_s, 72, 16, 16, w, c16, q, lofs, naA, Wp1hi, Wp1lo, part_s);
    __syncthreads();
    for (int t = tid; t < 1024; t += 256) {
        int row = t >> 6, col = t & 63;
        float v = part_s[0][row][col] + part_s[1][row][col] + part_s[2][row][col] +
                  part_s[3][row][col] + bp1[col];
        u1_s[row * 72 + col] = __float2bfloat16(silu_f(v));
    }
    __syncthreads();
    zgemm_stage(u1_s, 72, 16, 16, w, c16, q, lofs, naA, Wp2hi, Wp2lo, part_s);
    __syncthreads();
    for (int t = tid; t < 1024; t += 256) {
        int row = t >> 6, col = t & 63;
        float v = part_s[0][row][col] + part_s[1][row][col] + part_s[2][row][col] +
                  part_s[3][row][col] + bp2[col];
        p2[(size_t)(n0 + row) * 64 + col] = v;
    }
}

// ---------------- K_pool ----------------
__global__ __launch_bounds__(256) void k_pool(
        const float* __restrict__ p2, const int* __restrict__ batch,
        float* __restrict__ partial_p, float* __restrict__ partial_cnt) {
    __shared__ float acc_s[16 * 64];
    __shared__ float cnt_s[16];
    int tid = threadIdx.x;
    for (int idx = tid; idx < 1024; idx += 256) acc_s[idx] = 0.f;
    if (tid < 16) cnt_s[tid] = 0.f;
    __syncthreads();
    int w = tid >> 6, k = tid & 63;
    int base = blockIdx.x * 125;
    for (int i = 0; i < 32; ++i) {
        int nl = i * 4 + w;
        if (nl < 125) {
            int n = base + nl;
            int b = batch[n];
            atomicAdd(&acc_s[b * 64 + k], p2[(size_t)n * 64 + k]);
            if (k == 0) atomicAdd(&cnt_s[b], 1.0f);
        }
    }
    __syncthreads();
    for (int idx = tid; idx < 1024; idx += 256)
        partial_p[(size_t)blockIdx.x * 1024 + idx] = acc_s[idx];
    if (tid < 16) partial_cnt[blockIdx.x * 16 + tid] = cnt_s[tid];
}

// ---------------- K7: reduce partials, mean, final MLP ----------------
__global__ __launch_bounds__(1024) void k_final(
        const float* __restrict__ partial_p, const float* __restrict__ partial_cnt,
        const float* __restrict__ Wq1, const float* __restrict__ bq1,
        const float* __restrict__ Wq2, const float* __restrict__ bq2,
        float* __restrict__ out) {
    __shared__ float g[16][64];
    int b = threadIdx.x >> 6, k = threadIdx.x & 63;
    float s = 0.f, cc = 0.f;
    for (int c = 0; c < POOL_CHUNKS; ++c) s += partial_p[(size_t)c * 1024 + b * 64 + k];
    for (int c = 0; c < POOL_CHUNKS; ++c) cc += partial_cnt[c * 16 + b];
    g[b][k] = s / fmaxf(cc, 1.0f);
    __syncthreads();
    float acc = bq1[k];
#pragma unroll
    for (int i = 0; i < 64; ++i) acc = fmaf(g[b][i], Wq1[i * 64 + k], acc);
    float v = silu_f(acc) * Wq2[k];
#pragma unroll
    for (int off = 32; off > 0; off >>= 1) v += __shfl_down(v, off, 64);
    if (k == 0) out[b] = v + bq2[0];
}

extern "C" void kernel_launch(void* const* d_in, const int* in_sizes, int n_in,
                              void* d_out, int out_size, void* d_ws, size_t ws_size,
                              hipStream_t stream) {
    const float* x    = (const float*)d_in[0];
    const int*   eidx = (const int*)  d_in[1];
    const float* ea   = (const float*)d_in[2];
    const float* na   = (const float*)d_in[3];
    const float* amf  = (const float*)d_in[4];
    const float* anf  = (const float*)d_in[5];
    const int*   batch= (const int*)  d_in[6];
    const float* W_emb= (const float*)d_in[7];
    const float* b_emb= (const float*)d_in[8];
    const float* Wm1  = (const float*)d_in[9];
    const float* bm1  = (const float*)d_in[10];
    const float* Wm2  = (const float*)d_in[11];
    const float* bm2  = (const float*)d_in[12];
    const float* Wu1  = (const float*)d_in[13];
    const float* bu1  = (const float*)d_in[14];
    const float* Wu2  = (const float*)d_in[15];
    const float* bu2  = (const float*)d_in[16];
    const float* Wp1  = (const float*)d_in[17];
    const float* bp1  = (const float*)d_in[18];
    const float* Wp2  = (const float*)d_in[19];
    const float* bp2  = (const float*)d_in[20];
    const float* Wq1  = (const float*)d_in[21];
    const float* bq1  = (const float*)d_in[22];
    const float* Wq2  = (const float*)d_in[23];
    const float* bq2  = (const float*)d_in[24];

    float* ws = (float*)d_ws;
    float* h      = ws;                            // N*64
    float* agg    = h + (size_t)N * 64;            // N*64
    float* p2     = agg + (size_t)N * 64;          // N*64
    float* part_p = p2 + (size_t)N * 64;           // 80*1024
    float* part_c = part_p + POOL_CHUNKS * 1024;   // 80*16
    float* fend   = part_c + POOL_CHUNKS * 16;
    __hip_bfloat16* hb     = (__hip_bfloat16*)fend;          // N*96
    __hip_bfloat16* W2hi   = hb + (size_t)N * HS;            // 2*32768
    __hip_bfloat16* Wm1zhi = W2hi + 65536;                   // 2*71680
    __hip_bfloat16* Wu1hi  = Wm1zhi + 143360;                // 2*67584
    __hip_bfloat16* Wu1lo  = Wu1hi + 135168;
    __hip_bfloat16* Wu2hi  = Wu1lo + 135168;                 // 2*32768
    __hip_bfloat16* Wu2lo  = Wu2hi + 65536;
    __hip_bfloat16* Wp1hi  = Wu2lo + 65536;                  // 32768
    __hip_bfloat16* Wp1lo  = Wp1hi + 32768;
    __hip_bfloat16* Wp2hi  = Wp1lo + 32768;
    __hip_bfloat16* Wp2lo  = Wp2hi + 32768;
    int* hist   = (int*)(Wp2lo + 32768);                     // N
    int* cursor = hist + N;                                  // N
    int* dstS   = cursor + N;                                // E
    float4* recs = (float4*)(dstS + E);                      // E * 3 float4 (48B/edge)

    // mega pre-kernel: all weight reorders + hist zero + embed(+agg/hb init)
    k_pre<<<PB_TOTAL, 256, 0, stream>>>(
        Wm2, W2hi, Wm1, Wm1zhi, Wu1, Wu1hi, Wu1lo, Wu2, Wu2hi, Wu2lo,
        Wp1, Wp1hi, Wp1lo, Wp2, Wp2hi, Wp2lo, hist,
        x, anf, na, W_emb, b_emb, h, hb, agg);

    // dst-sort + materialize sorted edge records (reused by both edge dispatches)
    k_hist<<<(E + 255) / 256, 256, 0, stream>>>(eidx, hist);
    k_scan<<<1, 1024, 0, stream>>>(hist, cursor);
    k_scatter_sort<<<(E + 255) / 256, 256, 0, stream>>>(eidx, ea, amf, cursor, dstS, recs);

    k_edge<<<E / 128, 256, 0, stream>>>(recs, dstS, hb,
                                        Wm1zhi, bm1, W2hi, bm2, agg);
    k_upd_hb<<<625, 256, 0, stream>>>(h, anf, na, agg,
                                      Wu1hi, Wu1lo, bu1,
                                      Wu2hi, Wu2lo, bu2,
                                      h, hb, agg);
    k_edge<<<E / 128, 256, 0, stream>>>(recs, dstS, hb,
                                        Wm1zhi + 71680, bm1 + 64,
                                        W2hi + 32768, bm2 + 64, agg);
    k_upd_prepool<<<625, 256, 0, stream>>>(h, anf, na, agg,
                                           Wu1hi + 67584, Wu1lo + 67584, bu1 + 64,
                                           Wu2hi + 32768, Wu2lo + 32768, bu2 + 64,
                                           Wp1hi, Wp1lo, bp1, Wp2hi, Wp2lo, bp2, p2);
    k_pool<<<POOL_CHUNKS, 256, 0, stream>>>(p2, batch, part_p, part_c);
    k_final<<<1, 1024, 0, stream>>>(part_p, part_c, Wq1, bq1, Wq2, bq2, (float*)d_out);
}